// Round 11
// baseline (618.661 us; speedup 1.0000x reference)
//
#include <hip/hip_runtime.h>
#include <math.h>

// ---- problem constants ----
#define OUT_XT     0
#define OUT_GRID   33554432
#define OUT_REG    58720256
#define OUT_MOVED  58720264
#define FC1_K      576000

// scratch inside d_out (regions consumed before being overwritten):
#define WS_BUF1    0          // (8,8,125,125,16) -- inside X_t region
#define WS_BUF2    16000000   // (8,10,60,60,16)
#define WS_PART    20608000   // 2000 x 256
#define WS_RED     21120000   // 80 x 256
#define WS_RT      58720256   // 8x4x12 -- reg+moved region, overwritten by k_tail

// ======== prep: transpose weights into [ic][dd][oc] for contiguous uniform (s_load) reads ========
__global__ __launch_bounds__(256) void k_prep(const float* __restrict__ w1,
                                              const float* __restrict__ w2,
                                              float* __restrict__ wt1,
                                              float* __restrict__ wt2) {
  const int tid = threadIdx.x;
  for (int t = tid; t < 1568; t += 256) {
    int oc = t & 7, idx = t >> 3;
    int ic = idx / 49, dd = idx % 49;
    wt1[t] = w1[(oc * 4 + ic) * 49 + dd];
  }
  for (int t = tid; t < 2000; t += 256) {
    int oc = t % 10, idx = t / 10;
    int ic = idx / 25, dd = idx % 25;
    wt2[t] = w2[(oc * 8 + ic) * 25 + dd];
  }
}

// ================= conv1 (7x7x1, 4->8) + pool(2,2,1) + relu =================
#define C1_RS 16
#define C1_PS 226
__global__ __launch_bounds__(256) void k_conv1(const float* __restrict__ x,
                                               const float* __restrict__ wt1,
                                               const float* __restrict__ b1,
                                               float* __restrict__ buf1,
                                               int zbase) {
  __shared__ float sIn[2][16 * C1_PS];
  const int tid = threadIdx.x;
  const int tx = blockIdx.x, ty = blockIdx.y, b = blockIdx.z + zbase;

  const int k = tid & 15;
  const int pix = tid >> 4;
  const int pyl = pix >> 2, pxl = pix & 3;
  const int row0 = ty * 8, col0 = tx * 8;

  int sq[4], srow[4], scol[4], sbase[4];
  bool sval[4];
#pragma unroll
  for (int it = 0; it < 4; ++it) {
    int t = tid + it * 256;
    int q = t & 3, pos = t >> 2;
    int coli = pos % 14, rowi = pos / 14;
    sq[it] = q;
    srow[it] = row0 + rowi;
    scol[it] = col0 + coli;
    sbase[it] = rowi * C1_RS + coli;
    sval[it] = (t < 784) && (srow[it] < 256) && (scol[it] < 256);
  }

  const float4* __restrict__ x4 = reinterpret_cast<const float4*>(x);
  float4 st[4];

#define C1_LOAD(ICV) do {                                                    \
  _Pragma("unroll")                                                          \
  for (int it = 0; it < 4; ++it) {                                           \
    float4 v = make_float4(0.f, 0.f, 0.f, 0.f);                              \
    if (sval[it])                                                            \
      v = x4[(((b * 4 + (ICV)) * 256 + srow[it]) * 256 + scol[it]) * 4 + sq[it]]; \
    st[it] = v;                                                              \
  } } while (0)

#define C1_WRITE(S) do {                                                     \
  _Pragma("unroll")                                                          \
  for (int it = 0; it < 4; ++it) {                                           \
    if (it < 3 || tid < 16) {                                                \
      float* sp = &sIn[S][(4 * sq[it]) * C1_PS + sbase[it]];                 \
      sp[0 * C1_PS] = st[it].x;                                              \
      sp[1 * C1_PS] = st[it].y;                                              \
      sp[2 * C1_PS] = st[it].z;                                              \
      sp[3 * C1_PS] = st[it].w;                                              \
    }                                                                        \
  } } while (0)

  float acc[2][2][8];
#pragma unroll
  for (int a = 0; a < 2; ++a)
#pragma unroll
    for (int c = 0; c < 2; ++c)
#pragma unroll
      for (int oc = 0; oc < 8; ++oc) acc[a][c][oc] = 0.f;

  C1_LOAD(0);
  C1_WRITE(0);
  __syncthreads();
  int cur = 0;

#pragma unroll 1
  for (int ic = 0; ic < 4; ++ic) {
    if (ic < 3) C1_LOAD(ic + 1);
    const float* __restrict__ sc = sIn[cur];
#pragma unroll 1
    for (int dy = 0; dy < 7; ++dy) {
      float v[2][8];
#pragma unroll
      for (int a = 0; a < 2; ++a) {
        const int base = k * C1_PS + (2 * pyl + a + dy) * C1_RS + 2 * pxl;
#pragma unroll
        for (int j = 0; j < 4; ++j) {
          float2 f = *reinterpret_cast<const float2*>(&sc[base + 2 * j]);
          v[a][2 * j] = f.x;
          v[a][2 * j + 1] = f.y;
        }
      }
      const float* __restrict__ wd = wt1 + ic * 392 + dy * 56;   // uniform -> s_load
#pragma unroll
      for (int dx = 0; dx < 7; ++dx) {
#pragma unroll
        for (int a = 0; a < 2; ++a)
#pragma unroll
          for (int c = 0; c < 2; ++c) {
            const float val = v[a][c + dx];
#pragma unroll
            for (int oc = 0; oc < 8; ++oc)
              acc[a][c][oc] = fmaf(val, wd[dx * 8 + oc], acc[a][c][oc]);
          }
      }
    }
    if (ic < 3) {
      C1_WRITE(cur ^ 1);
      __syncthreads();
      cur ^= 1;
    }
  }
#undef C1_LOAD
#undef C1_WRITE

  const int py = ty * 4 + pyl, px = tx * 4 + pxl;
  if (py < 125 && px < 125) {
#pragma unroll
    for (int oc = 0; oc < 8; ++oc) {
      float m = fmaxf(fmaxf(acc[0][0][oc], acc[0][1][oc]),
                      fmaxf(acc[1][0][oc], acc[1][1][oc])) + b1[oc];
      buf1[(((b * 8 + oc) * 125 + py) * 125 + px) * 16 + k] = fmaxf(m, 0.f);
    }
  }
}

// ================= conv2 (5x5x1, 8->10) + pool + relu =================
#define C2_RS 16
#define C2_PS 194
__global__ __launch_bounds__(256) void k_conv2(const float* __restrict__ in,
                                               const float* __restrict__ wt2,
                                               const float* __restrict__ b2,
                                               float* __restrict__ buf2) {
  __shared__ float sIn[2][16 * C2_PS];
  const int tid = threadIdx.x;
  const int tx = blockIdx.x, ty = blockIdx.y, b = blockIdx.z;

  const int k = tid & 15;
  const int pix = tid >> 4;
  const int pyl = pix >> 2, pxl = pix & 3;
  const int row0 = ty * 8, col0 = tx * 8;

  int sq[3], srow[3], scol[3], sbase[3];
#pragma unroll
  for (int it = 0; it < 3; ++it) {
    int t = tid + it * 256;
    int q = t & 3, pos = t >> 2;
    int coli = pos % 12, rowi = pos / 12;
    sq[it] = q;
    srow[it] = row0 + rowi;
    scol[it] = col0 + coli;
    sbase[it] = rowi * C2_RS + coli;
  }

  const float4* __restrict__ in4 = reinterpret_cast<const float4*>(in);
  float4 st[3];

#define C2_LOAD(ICV) do {                                                    \
  _Pragma("unroll")                                                          \
  for (int it = 0; it < 3; ++it) {                                           \
    if (it < 2 || tid < 64)                                                  \
      st[it] = in4[(((b * 8 + (ICV)) * 125 + srow[it]) * 125 + scol[it]) * 4 + sq[it]]; \
  } } while (0)

#define C2_WRITE(S) do {                                                     \
  _Pragma("unroll")                                                          \
  for (int it = 0; it < 3; ++it) {                                           \
    if (it < 2 || tid < 64) {                                                \
      float* sp = &sIn[S][(4 * sq[it]) * C2_PS + sbase[it]];                 \
      sp[0 * C2_PS] = st[it].x;                                              \
      sp[1 * C2_PS] = st[it].y;                                              \
      sp[2 * C2_PS] = st[it].z;                                              \
      sp[3 * C2_PS] = st[it].w;                                              \
    }                                                                        \
  } } while (0)

  float acc[2][2][10];
#pragma unroll
  for (int a = 0; a < 2; ++a)
#pragma unroll
    for (int c = 0; c < 2; ++c)
#pragma unroll
      for (int oc = 0; oc < 10; ++oc) acc[a][c][oc] = 0.f;

  C2_LOAD(0);
  C2_WRITE(0);
  __syncthreads();
  int cur = 0;

#pragma unroll 1
  for (int ic = 0; ic < 8; ++ic) {
    if (ic < 7) C2_LOAD(ic + 1);
    const float* __restrict__ sc = sIn[cur];
#pragma unroll 1
    for (int dy = 0; dy < 5; ++dy) {
      float v[2][6];
#pragma unroll
      for (int a = 0; a < 2; ++a) {
        const int base = k * C2_PS + (2 * pyl + a + dy) * C2_RS + 2 * pxl;
#pragma unroll
        for (int j = 0; j < 3; ++j) {
          float2 f = *reinterpret_cast<const float2*>(&sc[base + 2 * j]);
          v[a][2 * j] = f.x;
          v[a][2 * j + 1] = f.y;
        }
      }
      const float* __restrict__ wd = wt2 + ic * 250 + dy * 50;   // uniform -> s_load
#pragma unroll
      for (int dx = 0; dx < 5; ++dx) {
#pragma unroll
        for (int a = 0; a < 2; ++a)
#pragma unroll
          for (int c = 0; c < 2; ++c) {
            const float val = v[a][c + dx];
#pragma unroll
            for (int oc = 0; oc < 10; ++oc)
              acc[a][c][oc] = fmaf(val, wd[dx * 10 + oc], acc[a][c][oc]);
          }
      }
    }
    if (ic < 7) {
      C2_WRITE(cur ^ 1);
      __syncthreads();
      cur ^= 1;
    }
  }
#undef C2_LOAD
#undef C2_WRITE

  const int py = ty * 4 + pyl, px = tx * 4 + pxl;
#pragma unroll
  for (int oc = 0; oc < 10; ++oc) {
    float m = fmaxf(fmaxf(acc[0][0][oc], acc[0][1][oc]),
                    fmaxf(acc[1][0][oc], acc[1][1][oc])) + b2[oc];
    buf2[(((b * 10 + oc) * 60 + py) * 60 + px) * 16 + k] = fmaxf(m, 0.f);
  }
}

// ================= fc1 split-K pass 1: partial[2000][256], float4 loads =================
__global__ __launch_bounds__(256) void k_fc1(const float* __restrict__ z,
                                             const float* __restrict__ w,
                                             float* __restrict__ partial) {
  const int bid = blockIdx.x, tid = threadIdx.x;
  const int b = tid >> 5, o = tid & 31;
  const int k0 = bid * 288;                 // 2000 * 288 == 576000
  const float4* __restrict__ zp = reinterpret_cast<const float4*>(z + b * FC1_K + k0);
  const float4* __restrict__ wp = reinterpret_cast<const float4*>(w + o * FC1_K + k0);
  float a0 = 0.f, a1 = 0.f, a2 = 0.f, a3 = 0.f;
  float a4 = 0.f, a5 = 0.f, a6 = 0.f, a7 = 0.f;
#pragma unroll 2
  for (int i = 0; i < 72; i += 2) {
    float4 z0 = zp[i], w0 = wp[i];
    float4 z1 = zp[i + 1], w1 = wp[i + 1];
    a0 = fmaf(z0.x, w0.x, a0);
    a1 = fmaf(z0.y, w0.y, a1);
    a2 = fmaf(z0.z, w0.z, a2);
    a3 = fmaf(z0.w, w0.w, a3);
    a4 = fmaf(z1.x, w1.x, a4);
    a5 = fmaf(z1.y, w1.y, a5);
    a6 = fmaf(z1.z, w1.z, a6);
    a7 = fmaf(z1.w, w1.w, a7);
  }
  partial[bid * 256 + tid] = ((a0 + a1) + (a2 + a3)) + ((a4 + a5) + (a6 + a7));
}

// ======== red: partial[2000][256] -> red[80][256] ========
__global__ __launch_bounds__(256) void k_red(const float* __restrict__ partial,
                                             float* __restrict__ red) {
  const int bl = blockIdx.x, tid = threadIdx.x;
  const float* __restrict__ p = partial + bl * 25 * 256 + tid;
  float s0 = 0.f, s1 = 0.f, s2 = 0.f, s3 = 0.f, s4 = 0.f;
#pragma unroll
  for (int i = 0; i < 25; i += 5) {
    s0 += p[i * 256];
    s1 += p[(i + 1) * 256];
    s2 += p[(i + 2) * 256];
    s3 += p[(i + 3) * 256];
    s4 += p[(i + 4) * 256];
  }
  red[bl * 256 + tid] = ((s0 + s1) + (s2 + s3)) + s4;
}

// ======== head: reduce red[80][256] -> fc1 relu -> fc2 tanh -> R, Tv ========
__global__ __launch_bounds__(256) void k_head(const float* __restrict__ red,
                                              const float* __restrict__ fc1_b,
                                              const float* __restrict__ fc2_w,
                                              const float* __restrict__ fc2_b,
                                              float* __restrict__ RT) {
  __shared__ float sH[256];
  __shared__ float sTh[8][24];
  const int tid = threadIdx.x;
  float s0 = 0.f, s1 = 0.f, s2 = 0.f, s3 = 0.f;
#pragma unroll
  for (int c = 0; c < 80; c += 4) {
    s0 += red[c * 256 + tid];
    s1 += red[(c + 1) * 256 + tid];
    s2 += red[(c + 2) * 256 + tid];
    s3 += red[(c + 3) * 256 + tid];
  }
  const int o = tid & 31;
  sH[tid] = fmaxf(((s0 + s1) + (s2 + s3)) + fc1_b[o], 0.f);
  __syncthreads();
  if (tid < 192) {
    int b = tid / 24, o2 = tid % 24;
    float a = fc2_b[o2];
#pragma unroll
    for (int i = 0; i < 32; ++i) a = fmaf(sH[b * 32 + i], fc2_w[o2 * 32 + i], a);
    sTh[b][o2] = tanhf(a);
  }
  __syncthreads();
  if (tid < 32) {
    const int b = tid >> 2, t = tid & 3;
    const float PI = 3.14159265358979323846f;
    float a0 = PI * sTh[b][t * 6 + 0];
    float a1 = PI * sTh[b][t * 6 + 1];
    float a2 = PI * sTh[b][t * 6 + 2];
    float t0 = sTh[b][t * 6 + 3], t1 = sTh[b][t * 6 + 4], t2 = sTh[b][t * 6 + 5];
    float c0 = cosf(a0), s0v = sinf(a0);
    float c1 = cosf(a1), s1v = sinf(a1);
    float c2 = cosf(a2), s2v = sinf(a2);
    float R[3][3];
    R[0][0] = c0 * c1;
    R[0][1] = c0 * s1v * s2v - s0v * c2;
    R[0][2] = c0 * s1v * c2 + s0v * s2v;
    R[1][0] = s0v * c1;
    R[1][1] = s0v * s1v * s2v + c0 * c2;
    R[1][2] = s0v * s1v * c2 - c0 * s2v;
    R[2][0] = -s1v;
    R[2][1] = c1 * s2v;
    R[2][2] = c1 * c2;
    const float SZv[3] = {256.f, 256.f, 16.f};
    const float cen[3] = {128.f, 128.f, 8.f};
    const float tr[3] = {t0, t1, t2};
    float* rt = RT + (b * 4 + t) * 12;
#pragma unroll
    for (int kq = 0; kq < 3; ++kq)
#pragma unroll
      for (int s = 0; s < 3; ++s) rt[kq * 3 + s] = R[kq][s];
#pragma unroll
    for (int s = 0; s < 3; ++s)
      rt[9 + s] = tr[s] * SZv[s] + cen[s] - (128.f * R[0][s] + 128.f * R[1][s] + 8.f * R[2][s]);
  }
}

// ====== flow + grid_out + trilinear grid-sample -> X_t ======
// R11 single-variable A/B vs R10: ALL nontemporal store hints removed (stores now
// complete at L2 instead of HBM; NT completion latency was the remaining suspect).
__global__ __launch_bounds__(256) void k_flow(const float* __restrict__ x,
                                              const float* __restrict__ RT,
                                              float* __restrict__ out) {
  __shared__ float sg[768];
  const int raw = blockIdx.x;
  const int bid = (raw & 7) * 4096 + (raw >> 3);   // XCD gets contiguous chunk
  const int tid = threadIdx.x;
  const int b = bid >> 12;
  const int lblk = (bid & 4095) << 8;
  const int l = lblk | tid;
  const int i = l >> 12, j = (l >> 4) & 255, k = l & 15;
  const float fi = (float)i, fj = (float)j, fk = (float)k;
  const float* __restrict__ rt = RT + b * 48;

  const float txs[4] = {64.f, 64.f, 192.f, 192.f};
  const float tys[4] = {64.f, 192.f, 64.f, 192.f};
  float e[4], es = 0.f;
#pragma unroll
  for (int t = 0; t < 4; ++t) {
    float dx = fi - txs[t], dy = fj - tys[t], dz = fk - 8.f;
    float d = __builtin_amdgcn_sqrtf(fmaf(dx, dx, fmaf(dy, dy, dz * dz)));
    e[t] = __expf(-0.1f * d);
    es += e[t];
  }
  float inv = __builtin_amdgcn_rcpf(es);
  float f0 = 0.f, f1 = 0.f, f2 = 0.f;
#pragma unroll
  for (int t = 0; t < 4; ++t) {
    float wt = e[t] * inv;
    const float* r = rt + t * 12;
    f0 += wt * (fi * r[0] + fj * r[3] + fk * r[6] + r[9]);
    f1 += wt * (fi * r[1] + fj * r[4] + fk * r[7] + r[10]);
    f2 += wt * (fi * r[2] + fj * r[5] + fk * r[8] + r[11]);
  }
  float nf0 = f0 * (1.f / 128.f) - 1.f;
  float nf1 = f1 * (1.f / 128.f) - 1.f;
  float nf2 = f2 * 0.125f - 1.f;

  // grid_out via LDS bounce -> 3 fully-coalesced 1KB/wave streams
  sg[tid * 3 + 0] = nf2;
  sg[tid * 3 + 1] = nf1;
  sg[tid * 3 + 2] = nf0;
  __syncthreads();
  {
    float* gb = out + OUT_GRID + ((size_t)(b << 20) + lblk) * 3;
    gb[tid] = sg[tid];
    gb[tid + 256] = sg[tid + 256];
    gb[tid + 512] = sg[tid + 512];
  }

  float ix = ((nf2 + 1.f) * 16.f - 1.f) * 0.5f;
  float iy = ((nf1 + 1.f) * 256.f - 1.f) * 0.5f;
  float iz = ((nf0 + 1.f) * 256.f - 1.f) * 0.5f;
  float xf = floorf(ix), yf = floorf(iy), zf = floorf(iz);
  float fx = ix - xf, fy = iy - yf, fz = iz - zf;
  int x0 = (int)xf, y0 = (int)yf, z0 = (int)zf;
  int x1 = x0 + 1, y1 = y0 + 1, z1 = z0 + 1;
  bool vx0 = ((unsigned)x0 < 16u), vx1 = ((unsigned)x1 < 16u);
  bool vy0 = ((unsigned)y0 < 256u), vy1 = ((unsigned)y1 < 256u);
  bool vz0 = ((unsigned)z0 < 256u), vz1 = ((unsigned)z1 < 256u);
  int cx0 = min(max(x0, 0), 15), cx1 = min(max(x1, 0), 15);
  int cy0 = min(max(y0, 0), 255), cy1 = min(max(y1, 0), 255);
  int cz0 = min(max(z0, 0), 255), cz1 = min(max(z1, 0), 255);
  float wx0 = 1.f - fx, wx1 = fx, wy0 = 1.f - fy, wy1 = fy, wz0 = 1.f - fz, wz1 = fz;

  float W[8];
  W[0] = wz0 * wy0 * wx0 * ((vz0 && vy0 && vx0) ? 1.f : 0.f);
  W[1] = wz0 * wy0 * wx1 * ((vz0 && vy0 && vx1) ? 1.f : 0.f);
  W[2] = wz0 * wy1 * wx0 * ((vz0 && vy1 && vx0) ? 1.f : 0.f);
  W[3] = wz0 * wy1 * wx1 * ((vz0 && vy1 && vx1) ? 1.f : 0.f);
  W[4] = wz1 * wy0 * wx0 * ((vz1 && vy0 && vx0) ? 1.f : 0.f);
  W[5] = wz1 * wy0 * wx1 * ((vz1 && vy0 && vx1) ? 1.f : 0.f);
  W[6] = wz1 * wy1 * wx0 * ((vz1 && vy1 && vx0) ? 1.f : 0.f);
  W[7] = wz1 * wy1 * wx1 * ((vz1 && vy1 && vx1) ? 1.f : 0.f);

  int offs[8];
  offs[0] = (cz0 << 12) + (cy0 << 4) + cx0;
  offs[1] = (cz0 << 12) + (cy0 << 4) + cx1;
  offs[2] = (cz0 << 12) + (cy1 << 4) + cx0;
  offs[3] = (cz0 << 12) + (cy1 << 4) + cx1;
  offs[4] = (cz1 << 12) + (cy0 << 4) + cx0;
  offs[5] = (cz1 << 12) + (cy0 << 4) + cx1;
  offs[6] = (cz1 << 12) + (cy1 << 4) + cx0;
  offs[7] = (cz1 << 12) + (cy1 << 4) + cx1;

  const float* __restrict__ xb0 = x + ((size_t)(b * 4) << 20);
  const float* __restrict__ xb1 = xb0 + (1 << 20);
  const float* __restrict__ xb2 = xb0 + (2 << 20);
  const float* __restrict__ xb3 = xb0 + (3 << 20);

  // channels 0,1: 16 loads forced into one clause by the asm use-all barrier
  {
    float va[8], vb[8];
#pragma unroll
    for (int q = 0; q < 8; ++q) va[q] = xb0[offs[q]];
#pragma unroll
    for (int q = 0; q < 8; ++q) vb[q] = xb1[offs[q]];
    asm volatile("" :: "v"(va[0]), "v"(va[1]), "v"(va[2]), "v"(va[3]),
                       "v"(va[4]), "v"(va[5]), "v"(va[6]), "v"(va[7]),
                       "v"(vb[0]), "v"(vb[1]), "v"(vb[2]), "v"(vb[3]),
                       "v"(vb[4]), "v"(vb[5]), "v"(vb[6]), "v"(vb[7]));
    float s0 = 0.f, s1 = 0.f;
#pragma unroll
    for (int q = 0; q < 8; ++q) {
      s0 = fmaf(W[q], va[q], s0);
      s1 = fmaf(W[q], vb[q], s1);
    }
    out[OUT_XT + ((b * 4 + 0) << 20) + l] = s0;
    out[OUT_XT + ((b * 4 + 1) << 20) + l] = s1;
  }
  // channels 2,3
  {
    float va[8], vb[8];
#pragma unroll
    for (int q = 0; q < 8; ++q) va[q] = xb2[offs[q]];
#pragma unroll
    for (int q = 0; q < 8; ++q) vb[q] = xb3[offs[q]];
    asm volatile("" :: "v"(va[0]), "v"(va[1]), "v"(va[2]), "v"(va[3]),
                       "v"(va[4]), "v"(va[5]), "v"(va[6]), "v"(va[7]),
                       "v"(vb[0]), "v"(vb[1]), "v"(vb[2]), "v"(vb[3]),
                       "v"(vb[4]), "v"(vb[5]), "v"(vb[6]), "v"(vb[7]));
    float s0 = 0.f, s1 = 0.f;
#pragma unroll
    for (int q = 0; q < 8; ++q) {
      s0 = fmaf(W[q], va[q], s0);
      s1 = fmaf(W[q], vb[q], s1);
    }
    out[OUT_XT + ((b * 4 + 2) << 20) + l] = s0;
    out[OUT_XT + ((b * 4 + 3) << 20) + l] = s1;
  }
}

// ====== moved + reg ======
__global__ __launch_bounds__(256) void k_tail(const float* __restrict__ P,
                                              const float* __restrict__ centers,
                                              const int* __restrict__ times,
                                              float* __restrict__ out) {
  const int b = blockIdx.x, tid = threadIdx.x;
  __shared__ float sred[256];
  float nrm = 0.f;
  if (tid < 200) {
    int tb = times[b];
    float p0 = P[tid * 96 + tb];
    float p1 = P[tid * 96 + 32 + tb];
    float p2 = P[tid * 96 + 64 + tb];
    int i0 = (int)rintf(p0), i1 = (int)rintf(p1), i2 = (int)rintf(p2);
    int lp = (i0 << 12) + (i1 << 4) + i2;
    int gb = OUT_GRID + ((b << 20) + lp) * 3;
    float a0 = out[gb + 2];
    float a1 = out[gb + 1];
    float a2 = out[gb + 0];
    float m0 = 2.f * p0 - (0.5f + 0.5f * a0) * 255.f;
    float m1 = 2.f * p1 - (0.5f + 0.5f * a1) * 255.f;
    float m2 = 2.f * p2 - (0.5f + 0.5f * a2) * 15.f;
    int mo = OUT_MOVED + (b * 200 + tid) * 3;
    out[mo] = m0;
    out[mo + 1] = m1;
    out[mo + 2] = m2;
    float d0 = m0 - centers[tid * 3];
    float d1 = m1 - centers[tid * 3 + 1];
    float d2 = m2 - centers[tid * 3 + 2];
    nrm = sqrtf(d0 * d0 + d1 * d1 + d2 * d2);
  }
  sred[tid] = nrm;
  __syncthreads();
  for (int s = 128; s > 0; s >>= 1) {
    if (tid < s) sred[tid] += sred[tid + s];
    __syncthreads();
  }
  if (tid == 0) out[OUT_REG + b] = sred[0] * 0.005f;
}

extern "C" void kernel_launch(void* const* d_in, const int* in_sizes, int n_in,
                              void* d_out, int out_size, void* d_ws, size_t ws_size,
                              hipStream_t stream) {
  const float* x = (const float*)d_in[0];
  const int* times = (const int*)d_in[1];
  const float* w1 = (const float*)d_in[2];
  const float* b1 = (const float*)d_in[3];
  const float* w2 = (const float*)d_in[4];
  const float* b2 = (const float*)d_in[5];
  const float* fw1 = (const float*)d_in[6];
  const float* fb1 = (const float*)d_in[7];
  const float* fw2 = (const float*)d_in[8];
  const float* fb2 = (const float*)d_in[9];
  const float* P = (const float*)d_in[10];
  const float* centers = (const float*)d_in[11];
  float* out = (float*)d_out;

  float* wt1 = (float*)d_ws;          // 1568 floats
  float* wt2 = wt1 + 1568;            // 2000 floats

  float* buf1 = out + WS_BUF1;
  float* buf2 = out + WS_BUF2;
  float* partial = out + WS_PART;
  float* red = out + WS_RED;
  float* RT = out + WS_RT;

  k_prep<<<1, 256, 0, stream>>>(w1, w2, wt1, wt2);
  for (int zb = 0; zb < 8; zb += 4)
    k_conv1<<<dim3(32, 32, 4), 256, 0, stream>>>(x, wt1, b1, buf1, zb);
  k_conv2<<<dim3(15, 15, 8), 256, 0, stream>>>(buf1, wt2, b2, buf2);
  k_fc1<<<2000, 256, 0, stream>>>(buf2, fw1, partial);
  k_red<<<80, 256, 0, stream>>>(partial, red);
  k_head<<<1, 256, 0, stream>>>(red, fb1, fw2, fb2, RT);
  k_flow<<<32768, 256, 0, stream>>>(x, RT, out);
  k_tail<<<8, 256, 0, stream>>>(P, centers, times, out);
}

// Round 12
// 601.542 us; speedup vs baseline: 1.0285x; 1.0285x over previous
//
#include <hip/hip_runtime.h>
#include <math.h>

// ---- problem constants ----
#define OUT_XT     0
#define OUT_GRID   33554432
#define OUT_REG    58720256
#define OUT_MOVED  58720264
#define FC1_K      576000

// scratch inside d_out (regions consumed before being overwritten):
#define WS_BUF1    0          // (8,8,125,125,16) -- inside X_t region
#define WS_BUF2    16000000   // (8,10,60,60,16)
#define WS_PART    20608000   // 2000 x 256
#define WS_RED     21120000   // 80 x 256
#define WS_RT      58720256   // 8x4x12 -- reg+moved region, overwritten by k_tail

// ======== prep: transpose weights into [ic][dd][oc] for contiguous uniform (s_load) reads ========
__global__ __launch_bounds__(256) void k_prep(const float* __restrict__ w1,
                                              const float* __restrict__ w2,
                                              float* __restrict__ wt1,
                                              float* __restrict__ wt2) {
  const int tid = threadIdx.x;
  for (int t = tid; t < 1568; t += 256) {
    int oc = t & 7, idx = t >> 3;
    int ic = idx / 49, dd = idx % 49;
    wt1[t] = w1[(oc * 4 + ic) * 49 + dd];
  }
  for (int t = tid; t < 2000; t += 256) {
    int oc = t % 10, idx = t / 10;
    int ic = idx / 25, dd = idx % 25;
    wt2[t] = w2[(oc * 8 + ic) * 25 + dd];
  }
}

// ================= conv1 (7x7x1, 4->8) + pool(2,2,1) + relu =================
#define C1_RS 16
#define C1_PS 226
__global__ __launch_bounds__(256) void k_conv1(const float* __restrict__ x,
                                               const float* __restrict__ wt1,
                                               const float* __restrict__ b1,
                                               float* __restrict__ buf1,
                                               int zbase) {
  __shared__ float sIn[2][16 * C1_PS];
  const int tid = threadIdx.x;
  const int tx = blockIdx.x, ty = blockIdx.y, b = blockIdx.z + zbase;

  const int k = tid & 15;
  const int pix = tid >> 4;
  const int pyl = pix >> 2, pxl = pix & 3;
  const int row0 = ty * 8, col0 = tx * 8;

  int sq[4], srow[4], scol[4], sbase[4];
  bool sval[4];
#pragma unroll
  for (int it = 0; it < 4; ++it) {
    int t = tid + it * 256;
    int q = t & 3, pos = t >> 2;
    int coli = pos % 14, rowi = pos / 14;
    sq[it] = q;
    srow[it] = row0 + rowi;
    scol[it] = col0 + coli;
    sbase[it] = rowi * C1_RS + coli;
    sval[it] = (t < 784) && (srow[it] < 256) && (scol[it] < 256);
  }

  const float4* __restrict__ x4 = reinterpret_cast<const float4*>(x);
  float4 st[4];

#define C1_LOAD(ICV) do {                                                    \
  _Pragma("unroll")                                                          \
  for (int it = 0; it < 4; ++it) {                                           \
    float4 v = make_float4(0.f, 0.f, 0.f, 0.f);                              \
    if (sval[it])                                                            \
      v = x4[(((b * 4 + (ICV)) * 256 + srow[it]) * 256 + scol[it]) * 4 + sq[it]]; \
    st[it] = v;                                                              \
  } } while (0)

#define C1_WRITE(S) do {                                                     \
  _Pragma("unroll")                                                          \
  for (int it = 0; it < 4; ++it) {                                           \
    if (it < 3 || tid < 16) {                                                \
      float* sp = &sIn[S][(4 * sq[it]) * C1_PS + sbase[it]];                 \
      sp[0 * C1_PS] = st[it].x;                                              \
      sp[1 * C1_PS] = st[it].y;                                              \
      sp[2 * C1_PS] = st[it].z;                                              \
      sp[3 * C1_PS] = st[it].w;                                              \
    }                                                                        \
  } } while (0)

  float acc[2][2][8];
#pragma unroll
  for (int a = 0; a < 2; ++a)
#pragma unroll
    for (int c = 0; c < 2; ++c)
#pragma unroll
      for (int oc = 0; oc < 8; ++oc) acc[a][c][oc] = 0.f;

  C1_LOAD(0);
  C1_WRITE(0);
  __syncthreads();
  int cur = 0;

#pragma unroll 1
  for (int ic = 0; ic < 4; ++ic) {
    if (ic < 3) C1_LOAD(ic + 1);
    const float* __restrict__ sc = sIn[cur];
#pragma unroll 1
    for (int dy = 0; dy < 7; ++dy) {
      float v[2][8];
#pragma unroll
      for (int a = 0; a < 2; ++a) {
        const int base = k * C1_PS + (2 * pyl + a + dy) * C1_RS + 2 * pxl;
#pragma unroll
        for (int j = 0; j < 4; ++j) {
          float2 f = *reinterpret_cast<const float2*>(&sc[base + 2 * j]);
          v[a][2 * j] = f.x;
          v[a][2 * j + 1] = f.y;
        }
      }
      const float* __restrict__ wd = wt1 + ic * 392 + dy * 56;   // uniform -> s_load
#pragma unroll
      for (int dx = 0; dx < 7; ++dx) {
#pragma unroll
        for (int a = 0; a < 2; ++a)
#pragma unroll
          for (int c = 0; c < 2; ++c) {
            const float val = v[a][c + dx];
#pragma unroll
            for (int oc = 0; oc < 8; ++oc)
              acc[a][c][oc] = fmaf(val, wd[dx * 8 + oc], acc[a][c][oc]);
          }
      }
    }
    if (ic < 3) {
      C1_WRITE(cur ^ 1);
      __syncthreads();
      cur ^= 1;
    }
  }
#undef C1_LOAD
#undef C1_WRITE

  const int py = ty * 4 + pyl, px = tx * 4 + pxl;
  if (py < 125 && px < 125) {
#pragma unroll
    for (int oc = 0; oc < 8; ++oc) {
      float m = fmaxf(fmaxf(acc[0][0][oc], acc[0][1][oc]),
                      fmaxf(acc[1][0][oc], acc[1][1][oc])) + b1[oc];
      buf1[(((b * 8 + oc) * 125 + py) * 125 + px) * 16 + k] = fmaxf(m, 0.f);
    }
  }
}

// ================= conv2 (5x5x1, 8->10) + pool + relu =================
#define C2_RS 16
#define C2_PS 194
__global__ __launch_bounds__(256) void k_conv2(const float* __restrict__ in,
                                               const float* __restrict__ wt2,
                                               const float* __restrict__ b2,
                                               float* __restrict__ buf2) {
  __shared__ float sIn[2][16 * C2_PS];
  const int tid = threadIdx.x;
  const int tx = blockIdx.x, ty = blockIdx.y, b = blockIdx.z;

  const int k = tid & 15;
  const int pix = tid >> 4;
  const int pyl = pix >> 2, pxl = pix & 3;
  const int row0 = ty * 8, col0 = tx * 8;

  int sq[3], srow[3], scol[3], sbase[3];
#pragma unroll
  for (int it = 0; it < 3; ++it) {
    int t = tid + it * 256;
    int q = t & 3, pos = t >> 2;
    int coli = pos % 12, rowi = pos / 12;
    sq[it] = q;
    srow[it] = row0 + rowi;
    scol[it] = col0 + coli;
    sbase[it] = rowi * C2_RS + coli;
  }

  const float4* __restrict__ in4 = reinterpret_cast<const float4*>(in);
  float4 st[3];

#define C2_LOAD(ICV) do {                                                    \
  _Pragma("unroll")                                                          \
  for (int it = 0; it < 3; ++it) {                                           \
    if (it < 2 || tid < 64)                                                  \
      st[it] = in4[(((b * 8 + (ICV)) * 125 + srow[it]) * 125 + scol[it]) * 4 + sq[it]]; \
  } } while (0)

#define C2_WRITE(S) do {                                                     \
  _Pragma("unroll")                                                          \
  for (int it = 0; it < 3; ++it) {                                           \
    if (it < 2 || tid < 64) {                                                \
      float* sp = &sIn[S][(4 * sq[it]) * C2_PS + sbase[it]];                 \
      sp[0 * C2_PS] = st[it].x;                                              \
      sp[1 * C2_PS] = st[it].y;                                              \
      sp[2 * C2_PS] = st[it].z;                                              \
      sp[3 * C2_PS] = st[it].w;                                              \
    }                                                                        \
  } } while (0)

  float acc[2][2][10];
#pragma unroll
  for (int a = 0; a < 2; ++a)
#pragma unroll
    for (int c = 0; c < 2; ++c)
#pragma unroll
      for (int oc = 0; oc < 10; ++oc) acc[a][c][oc] = 0.f;

  C2_LOAD(0);
  C2_WRITE(0);
  __syncthreads();
  int cur = 0;

#pragma unroll 1
  for (int ic = 0; ic < 8; ++ic) {
    if (ic < 7) C2_LOAD(ic + 1);
    const float* __restrict__ sc = sIn[cur];
#pragma unroll 1
    for (int dy = 0; dy < 5; ++dy) {
      float v[2][6];
#pragma unroll
      for (int a = 0; a < 2; ++a) {
        const int base = k * C2_PS + (2 * pyl + a + dy) * C2_RS + 2 * pxl;
#pragma unroll
        for (int j = 0; j < 3; ++j) {
          float2 f = *reinterpret_cast<const float2*>(&sc[base + 2 * j]);
          v[a][2 * j] = f.x;
          v[a][2 * j + 1] = f.y;
        }
      }
      const float* __restrict__ wd = wt2 + ic * 250 + dy * 50;   // uniform -> s_load
#pragma unroll
      for (int dx = 0; dx < 5; ++dx) {
#pragma unroll
        for (int a = 0; a < 2; ++a)
#pragma unroll
          for (int c = 0; c < 2; ++c) {
            const float val = v[a][c + dx];
#pragma unroll
            for (int oc = 0; oc < 10; ++oc)
              acc[a][c][oc] = fmaf(val, wd[dx * 10 + oc], acc[a][c][oc]);
          }
      }
    }
    if (ic < 7) {
      C2_WRITE(cur ^ 1);
      __syncthreads();
      cur ^= 1;
    }
  }
#undef C2_LOAD
#undef C2_WRITE

  const int py = ty * 4 + pyl, px = tx * 4 + pxl;
#pragma unroll
  for (int oc = 0; oc < 10; ++oc) {
    float m = fmaxf(fmaxf(acc[0][0][oc], acc[0][1][oc]),
                    fmaxf(acc[1][0][oc], acc[1][1][oc])) + b2[oc];
    buf2[(((b * 10 + oc) * 60 + py) * 60 + px) * 16 + k] = fmaxf(m, 0.f);
  }
}

// ================= fc1 split-K pass 1: partial[2000][256], float4 loads =================
__global__ __launch_bounds__(256) void k_fc1(const float* __restrict__ z,
                                             const float* __restrict__ w,
                                             float* __restrict__ partial) {
  const int bid = blockIdx.x, tid = threadIdx.x;
  const int b = tid >> 5, o = tid & 31;
  const int k0 = bid * 288;                 // 2000 * 288 == 576000
  const float4* __restrict__ zp = reinterpret_cast<const float4*>(z + b * FC1_K + k0);
  const float4* __restrict__ wp = reinterpret_cast<const float4*>(w + o * FC1_K + k0);
  float a0 = 0.f, a1 = 0.f, a2 = 0.f, a3 = 0.f;
  float a4 = 0.f, a5 = 0.f, a6 = 0.f, a7 = 0.f;
#pragma unroll 2
  for (int i = 0; i < 72; i += 2) {
    float4 z0 = zp[i], w0 = wp[i];
    float4 z1 = zp[i + 1], w1 = wp[i + 1];
    a0 = fmaf(z0.x, w0.x, a0);
    a1 = fmaf(z0.y, w0.y, a1);
    a2 = fmaf(z0.z, w0.z, a2);
    a3 = fmaf(z0.w, w0.w, a3);
    a4 = fmaf(z1.x, w1.x, a4);
    a5 = fmaf(z1.y, w1.y, a5);
    a6 = fmaf(z1.z, w1.z, a6);
    a7 = fmaf(z1.w, w1.w, a7);
  }
  partial[bid * 256 + tid] = ((a0 + a1) + (a2 + a3)) + ((a4 + a5) + (a6 + a7));
}

// ======== red: partial[2000][256] -> red[80][256] ========
__global__ __launch_bounds__(256) void k_red(const float* __restrict__ partial,
                                             float* __restrict__ red) {
  const int bl = blockIdx.x, tid = threadIdx.x;
  const float* __restrict__ p = partial + bl * 25 * 256 + tid;
  float s0 = 0.f, s1 = 0.f, s2 = 0.f, s3 = 0.f, s4 = 0.f;
#pragma unroll
  for (int i = 0; i < 25; i += 5) {
    s0 += p[i * 256];
    s1 += p[(i + 1) * 256];
    s2 += p[(i + 2) * 256];
    s3 += p[(i + 3) * 256];
    s4 += p[(i + 4) * 256];
  }
  red[bl * 256 + tid] = ((s0 + s1) + (s2 + s3)) + s4;
}

// ======== head: reduce red[80][256] -> fc1 relu -> fc2 tanh -> R, Tv ========
__global__ __launch_bounds__(256) void k_head(const float* __restrict__ red,
                                              const float* __restrict__ fc1_b,
                                              const float* __restrict__ fc2_w,
                                              const float* __restrict__ fc2_b,
                                              float* __restrict__ RT) {
  __shared__ float sH[256];
  __shared__ float sTh[8][24];
  const int tid = threadIdx.x;
  float s0 = 0.f, s1 = 0.f, s2 = 0.f, s3 = 0.f;
#pragma unroll
  for (int c = 0; c < 80; c += 4) {
    s0 += red[c * 256 + tid];
    s1 += red[(c + 1) * 256 + tid];
    s2 += red[(c + 2) * 256 + tid];
    s3 += red[(c + 3) * 256 + tid];
  }
  const int o = tid & 31;
  sH[tid] = fmaxf(((s0 + s1) + (s2 + s3)) + fc1_b[o], 0.f);
  __syncthreads();
  if (tid < 192) {
    int b = tid / 24, o2 = tid % 24;
    float a = fc2_b[o2];
#pragma unroll
    for (int i = 0; i < 32; ++i) a = fmaf(sH[b * 32 + i], fc2_w[o2 * 32 + i], a);
    sTh[b][o2] = tanhf(a);
  }
  __syncthreads();
  if (tid < 32) {
    const int b = tid >> 2, t = tid & 3;
    const float PI = 3.14159265358979323846f;
    float a0 = PI * sTh[b][t * 6 + 0];
    float a1 = PI * sTh[b][t * 6 + 1];
    float a2 = PI * sTh[b][t * 6 + 2];
    float t0 = sTh[b][t * 6 + 3], t1 = sTh[b][t * 6 + 4], t2 = sTh[b][t * 6 + 5];
    float c0 = cosf(a0), s0v = sinf(a0);
    float c1 = cosf(a1), s1v = sinf(a1);
    float c2 = cosf(a2), s2v = sinf(a2);
    float R[3][3];
    R[0][0] = c0 * c1;
    R[0][1] = c0 * s1v * s2v - s0v * c2;
    R[0][2] = c0 * s1v * c2 + s0v * s2v;
    R[1][0] = s0v * c1;
    R[1][1] = s0v * s1v * s2v + c0 * c2;
    R[1][2] = s0v * s1v * c2 - c0 * s2v;
    R[2][0] = -s1v;
    R[2][1] = c1 * s2v;
    R[2][2] = c1 * c2;
    const float SZv[3] = {256.f, 256.f, 16.f};
    const float cen[3] = {128.f, 128.f, 8.f};
    const float tr[3] = {t0, t1, t2};
    float* rt = RT + (b * 4 + t) * 12;
#pragma unroll
    for (int kq = 0; kq < 3; ++kq)
#pragma unroll
      for (int s = 0; s < 3; ++s) rt[kq * 3 + s] = R[kq][s];
#pragma unroll
    for (int s = 0; s < 3; ++s)
      rt[9 + s] = tr[s] * SZv[s] + cen[s] - (128.f * R[0][s] + 128.f * R[1][s] + 8.f * R[2][s]);
  }
}

// ====== flow helper: one output point's transform + grid store + gather setup ======
__device__ __forceinline__ void flow_pt(int idx, int tid,
                                        const float* __restrict__ RT,
                                        float* __restrict__ out,
                                        int& bOut, int& lOut,
                                        float W[8], int offs[8]) {
  const int b = idx >> 12;
  const int l = ((idx & 4095) << 8) | tid;
  const int i = l >> 12, j = (l >> 4) & 255, k = l & 15;
  const float fi = (float)i, fj = (float)j, fk = (float)k;
  const float* __restrict__ rt = RT + b * 48;

  const float txs[4] = {64.f, 64.f, 192.f, 192.f};
  const float tys[4] = {64.f, 192.f, 64.f, 192.f};
  float e[4], es = 0.f;
#pragma unroll
  for (int t = 0; t < 4; ++t) {
    float dx = fi - txs[t], dy = fj - tys[t], dz = fk - 8.f;
    float d = __builtin_amdgcn_sqrtf(fmaf(dx, dx, fmaf(dy, dy, dz * dz)));
    e[t] = __expf(-0.1f * d);
    es += e[t];
  }
  float inv = __builtin_amdgcn_rcpf(es);
  float f0 = 0.f, f1 = 0.f, f2 = 0.f;
#pragma unroll
  for (int t = 0; t < 4; ++t) {
    float wt = e[t] * inv;
    const float* r = rt + t * 12;
    f0 += wt * (fi * r[0] + fj * r[3] + fk * r[6] + r[9]);
    f1 += wt * (fi * r[1] + fj * r[4] + fk * r[7] + r[10]);
    f2 += wt * (fi * r[2] + fj * r[5] + fk * r[8] + r[11]);
  }
  float nf0 = f0 * (1.f / 128.f) - 1.f;
  float nf1 = f1 * (1.f / 128.f) - 1.f;
  float nf2 = f2 * 0.125f - 1.f;

  int gbase = OUT_GRID + ((b << 20) + l) * 3;
  __builtin_nontemporal_store(nf2, &out[gbase]);
  __builtin_nontemporal_store(nf1, &out[gbase + 1]);
  __builtin_nontemporal_store(nf0, &out[gbase + 2]);

  float ix = ((nf2 + 1.f) * 16.f - 1.f) * 0.5f;
  float iy = ((nf1 + 1.f) * 256.f - 1.f) * 0.5f;
  float iz = ((nf0 + 1.f) * 256.f - 1.f) * 0.5f;
  float xf = floorf(ix), yf = floorf(iy), zf = floorf(iz);
  float fx = ix - xf, fy = iy - yf, fz = iz - zf;
  int x0 = (int)xf, y0 = (int)yf, z0 = (int)zf;
  int x1 = x0 + 1, y1 = y0 + 1, z1 = z0 + 1;
  bool vx0 = ((unsigned)x0 < 16u), vx1 = ((unsigned)x1 < 16u);
  bool vy0 = ((unsigned)y0 < 256u), vy1 = ((unsigned)y1 < 256u);
  bool vz0 = ((unsigned)z0 < 256u), vz1 = ((unsigned)z1 < 256u);
  int cx0 = min(max(x0, 0), 15), cx1 = min(max(x1, 0), 15);
  int cy0 = min(max(y0, 0), 255), cy1 = min(max(y1, 0), 255);
  int cz0 = min(max(z0, 0), 255), cz1 = min(max(z1, 0), 255);
  float wx0 = 1.f - fx, wx1 = fx, wy0 = 1.f - fy, wy1 = fy, wz0 = 1.f - fz, wz1 = fz;

  W[0] = wz0 * wy0 * wx0 * ((vz0 && vy0 && vx0) ? 1.f : 0.f);
  W[1] = wz0 * wy0 * wx1 * ((vz0 && vy0 && vx1) ? 1.f : 0.f);
  W[2] = wz0 * wy1 * wx0 * ((vz0 && vy1 && vx0) ? 1.f : 0.f);
  W[3] = wz0 * wy1 * wx1 * ((vz0 && vy1 && vx1) ? 1.f : 0.f);
  W[4] = wz1 * wy0 * wx0 * ((vz1 && vy0 && vx0) ? 1.f : 0.f);
  W[5] = wz1 * wy0 * wx1 * ((vz1 && vy0 && vx1) ? 1.f : 0.f);
  W[6] = wz1 * wy1 * wx0 * ((vz1 && vy1 && vx0) ? 1.f : 0.f);
  W[7] = wz1 * wy1 * wx1 * ((vz1 && vy1 && vx1) ? 1.f : 0.f);

  offs[0] = (cz0 << 12) + (cy0 << 4) + cx0;
  offs[1] = (cz0 << 12) + (cy0 << 4) + cx1;
  offs[2] = (cz0 << 12) + (cy1 << 4) + cx0;
  offs[3] = (cz0 << 12) + (cy1 << 4) + cx1;
  offs[4] = (cz1 << 12) + (cy0 << 4) + cx0;
  offs[5] = (cz1 << 12) + (cy0 << 4) + cx1;
  offs[6] = (cz1 << 12) + (cy1 << 4) + cx0;
  offs[7] = (cz1 << 12) + (cy1 << 4) + cx1;

  bOut = b;
  lOut = l;
}

// ====== flow: 2 points/thread, clause-level software pipeline ======
// A.c01 loads -> B.c01 loads -> reduce A.c01 / issue A.c23 -> reduce B.c01 /
// issue B.c23 -> reduce A.c23 -> reduce B.c23. Every waitcnt leaves >=16 loads
// in flight, keeping the texture-addresser fed (R8-R11: flow is VMEM
// transaction-rate + issue-starvation bound, not latency/BW/store bound).
__global__ __launch_bounds__(256) void k_flow(const float* __restrict__ x,
                                              const float* __restrict__ RT,
                                              float* __restrict__ out) {
  const int raw = blockIdx.x;                       // 16384 blocks
  const int swz = (raw & 7) * 2048 + (raw >> 3);    // XCD-contiguous
  const int tid = threadIdx.x;

  int bA, lA, bB, lB;
  float WA[8], WB[8];
  int oA[8], oB[8];
  flow_pt(swz * 2, tid, RT, out, bA, lA, WA, oA);
  flow_pt(swz * 2 + 1, tid, RT, out, bB, lB, WB, oB);

  const float* __restrict__ xA = x + ((size_t)(bA * 4) << 20);
  const float* __restrict__ xB = x + ((size_t)(bB * 4) << 20);

  float a0[8], a1[8], b0[8], b1[8];
  // A channels 0,1 (16 loads)
#pragma unroll
  for (int q = 0; q < 8; ++q) a0[q] = xA[oA[q]];
#pragma unroll
  for (int q = 0; q < 8; ++q) a1[q] = xA[(1 << 20) + oA[q]];
  // B channels 0,1 (16 loads; 32 outstanding)
#pragma unroll
  for (int q = 0; q < 8; ++q) b0[q] = xB[oB[q]];
#pragma unroll
  for (int q = 0; q < 8; ++q) b1[q] = xB[(1 << 20) + oB[q]];

  // reduce A.c01 (waits with B's 16 still in flight), store
  {
    float s0 = 0.f, s1 = 0.f;
#pragma unroll
    for (int q = 0; q < 8; ++q) {
      s0 = fmaf(WA[q], a0[q], s0);
      s1 = fmaf(WA[q], a1[q], s1);
    }
    __builtin_nontemporal_store(s0, &out[OUT_XT + ((bA * 4 + 0) << 20) + lA]);
    __builtin_nontemporal_store(s1, &out[OUT_XT + ((bA * 4 + 1) << 20) + lA]);
  }
  // A channels 2,3 reuse a0/a1
#pragma unroll
  for (int q = 0; q < 8; ++q) a0[q] = xA[(2 << 20) + oA[q]];
#pragma unroll
  for (int q = 0; q < 8; ++q) a1[q] = xA[(3 << 20) + oA[q]];

  // reduce B.c01, store
  {
    float s0 = 0.f, s1 = 0.f;
#pragma unroll
    for (int q = 0; q < 8; ++q) {
      s0 = fmaf(WB[q], b0[q], s0);
      s1 = fmaf(WB[q], b1[q], s1);
    }
    __builtin_nontemporal_store(s0, &out[OUT_XT + ((bB * 4 + 0) << 20) + lB]);
    __builtin_nontemporal_store(s1, &out[OUT_XT + ((bB * 4 + 1) << 20) + lB]);
  }
  // B channels 2,3
#pragma unroll
  for (int q = 0; q < 8; ++q) b0[q] = xB[(2 << 20) + oB[q]];
#pragma unroll
  for (int q = 0; q < 8; ++q) b1[q] = xB[(3 << 20) + oB[q]];

  // reduce A.c23, store
  {
    float s0 = 0.f, s1 = 0.f;
#pragma unroll
    for (int q = 0; q < 8; ++q) {
      s0 = fmaf(WA[q], a0[q], s0);
      s1 = fmaf(WA[q], a1[q], s1);
    }
    __builtin_nontemporal_store(s0, &out[OUT_XT + ((bA * 4 + 2) << 20) + lA]);
    __builtin_nontemporal_store(s1, &out[OUT_XT + ((bA * 4 + 3) << 20) + lA]);
  }
  // reduce B.c23, store
  {
    float s0 = 0.f, s1 = 0.f;
#pragma unroll
    for (int q = 0; q < 8; ++q) {
      s0 = fmaf(WB[q], b0[q], s0);
      s1 = fmaf(WB[q], b1[q], s1);
    }
    __builtin_nontemporal_store(s0, &out[OUT_XT + ((bB * 4 + 2) << 20) + lB]);
    __builtin_nontemporal_store(s1, &out[OUT_XT + ((bB * 4 + 3) << 20) + lB]);
  }
}

// ====== moved + reg ======
__global__ __launch_bounds__(256) void k_tail(const float* __restrict__ P,
                                              const float* __restrict__ centers,
                                              const int* __restrict__ times,
                                              float* __restrict__ out) {
  const int b = blockIdx.x, tid = threadIdx.x;
  __shared__ float sred[256];
  float nrm = 0.f;
  if (tid < 200) {
    int tb = times[b];
    float p0 = P[tid * 96 + tb];
    float p1 = P[tid * 96 + 32 + tb];
    float p2 = P[tid * 96 + 64 + tb];
    int i0 = (int)rintf(p0), i1 = (int)rintf(p1), i2 = (int)rintf(p2);
    int lp = (i0 << 12) + (i1 << 4) + i2;
    int gb = OUT_GRID + ((b << 20) + lp) * 3;
    float a0 = out[gb + 2];
    float a1 = out[gb + 1];
    float a2 = out[gb + 0];
    float m0 = 2.f * p0 - (0.5f + 0.5f * a0) * 255.f;
    float m1 = 2.f * p1 - (0.5f + 0.5f * a1) * 255.f;
    float m2 = 2.f * p2 - (0.5f + 0.5f * a2) * 15.f;
    int mo = OUT_MOVED + (b * 200 + tid) * 3;
    out[mo] = m0;
    out[mo + 1] = m1;
    out[mo + 2] = m2;
    float d0 = m0 - centers[tid * 3];
    float d1 = m1 - centers[tid * 3 + 1];
    float d2 = m2 - centers[tid * 3 + 2];
    nrm = sqrtf(d0 * d0 + d1 * d1 + d2 * d2);
  }
  sred[tid] = nrm;
  __syncthreads();
  for (int s = 128; s > 0; s >>= 1) {
    if (tid < s) sred[tid] += sred[tid + s];
    __syncthreads();
  }
  if (tid == 0) out[OUT_REG + b] = sred[0] * 0.005f;
}

extern "C" void kernel_launch(void* const* d_in, const int* in_sizes, int n_in,
                              void* d_out, int out_size, void* d_ws, size_t ws_size,
                              hipStream_t stream) {
  const float* x = (const float*)d_in[0];
  const int* times = (const int*)d_in[1];
  const float* w1 = (const float*)d_in[2];
  const float* b1 = (const float*)d_in[3];
  const float* w2 = (const float*)d_in[4];
  const float* b2 = (const float*)d_in[5];
  const float* fw1 = (const float*)d_in[6];
  const float* fb1 = (const float*)d_in[7];
  const float* fw2 = (const float*)d_in[8];
  const float* fb2 = (const float*)d_in[9];
  const float* P = (const float*)d_in[10];
  const float* centers = (const float*)d_in[11];
  float* out = (float*)d_out;

  float* wt1 = (float*)d_ws;          // 1568 floats
  float* wt2 = wt1 + 1568;            // 2000 floats

  float* buf1 = out + WS_BUF1;
  float* buf2 = out + WS_BUF2;
  float* partial = out + WS_PART;
  float* red = out + WS_RED;
  float* RT = out + WS_RT;

  k_prep<<<1, 256, 0, stream>>>(w1, w2, wt1, wt2);
  for (int zb = 0; zb < 8; zb += 4)
    k_conv1<<<dim3(32, 32, 4), 256, 0, stream>>>(x, wt1, b1, buf1, zb);
  k_conv2<<<dim3(15, 15, 8), 256, 0, stream>>>(buf1, wt2, b2, buf2);
  k_fc1<<<2000, 256, 0, stream>>>(buf2, fw1, partial);
  k_red<<<80, 256, 0, stream>>>(partial, red);
  k_head<<<1, 256, 0, stream>>>(red, fb1, fw2, fb2, RT);
  k_flow<<<16384, 256, 0, stream>>>(x, RT, out);
  k_tail<<<8, 256, 0, stream>>>(P, centers, times, out);
}

// Round 13
// 522.375 us; speedup vs baseline: 1.1843x; 1.1516x over previous
//
#include <hip/hip_runtime.h>
#include <math.h>

// ---- problem constants ----
#define OUT_XT     0
#define OUT_GRID   33554432
#define OUT_REG    58720256
#define OUT_MOVED  58720264
#define FC1_K      576000

// scratch inside d_out (regions consumed before being overwritten):
#define WS_BUF1    0          // (8,8,125,125,16) -- inside X_t region
#define WS_BUF2    16000000   // (8,10,60,60,16)
#define WS_PART    20608000   // 2000 x 256
#define WS_RED     21120000   // 80 x 256
#define WS_RT      58720256   // 8x4x12 -- reg+moved region, overwritten by k_tail

// ======== prep: transpose weights into [ic][dd][oc] for contiguous uniform (s_load) reads ========
__global__ __launch_bounds__(256) void k_prep(const float* __restrict__ w1,
                                              const float* __restrict__ w2,
                                              float* __restrict__ wt1,
                                              float* __restrict__ wt2) {
  const int tid = threadIdx.x;
  for (int t = tid; t < 1568; t += 256) {
    int oc = t & 7, idx = t >> 3;
    int ic = idx / 49, dd = idx % 49;
    wt1[t] = w1[(oc * 4 + ic) * 49 + dd];
  }
  for (int t = tid; t < 2000; t += 256) {
    int oc = t % 10, idx = t / 10;
    int ic = idx / 25, dd = idx % 25;
    wt2[t] = w2[(oc * 8 + ic) * 25 + dd];
  }
}

// ================= conv1 (7x7x1, 4->8) + pool(2,2,1) + relu =================
#define C1_RS 16
#define C1_PS 226
__global__ __launch_bounds__(256) void k_conv1(const float* __restrict__ x,
                                               const float* __restrict__ wt1,
                                               const float* __restrict__ b1,
                                               float* __restrict__ buf1,
                                               int zbase) {
  __shared__ float sIn[2][16 * C1_PS];
  const int tid = threadIdx.x;
  const int tx = blockIdx.x, ty = blockIdx.y, b = blockIdx.z + zbase;

  const int k = tid & 15;
  const int pix = tid >> 4;
  const int pyl = pix >> 2, pxl = pix & 3;
  const int row0 = ty * 8, col0 = tx * 8;

  int sq[4], srow[4], scol[4], sbase[4];
  bool sval[4];
#pragma unroll
  for (int it = 0; it < 4; ++it) {
    int t = tid + it * 256;
    int q = t & 3, pos = t >> 2;
    int coli = pos % 14, rowi = pos / 14;
    sq[it] = q;
    srow[it] = row0 + rowi;
    scol[it] = col0 + coli;
    sbase[it] = rowi * C1_RS + coli;
    sval[it] = (t < 784) && (srow[it] < 256) && (scol[it] < 256);
  }

  const float4* __restrict__ x4 = reinterpret_cast<const float4*>(x);
  float4 st[4];

#define C1_LOAD(ICV) do {                                                    \
  _Pragma("unroll")                                                          \
  for (int it = 0; it < 4; ++it) {                                           \
    float4 v = make_float4(0.f, 0.f, 0.f, 0.f);                              \
    if (sval[it])                                                            \
      v = x4[(((b * 4 + (ICV)) * 256 + srow[it]) * 256 + scol[it]) * 4 + sq[it]]; \
    st[it] = v;                                                              \
  } } while (0)

#define C1_WRITE(S) do {                                                     \
  _Pragma("unroll")                                                          \
  for (int it = 0; it < 4; ++it) {                                           \
    if (it < 3 || tid < 16) {                                                \
      float* sp = &sIn[S][(4 * sq[it]) * C1_PS + sbase[it]];                 \
      sp[0 * C1_PS] = st[it].x;                                              \
      sp[1 * C1_PS] = st[it].y;                                              \
      sp[2 * C1_PS] = st[it].z;                                              \
      sp[3 * C1_PS] = st[it].w;                                              \
    }                                                                        \
  } } while (0)

  float acc[2][2][8];
#pragma unroll
  for (int a = 0; a < 2; ++a)
#pragma unroll
    for (int c = 0; c < 2; ++c)
#pragma unroll
      for (int oc = 0; oc < 8; ++oc) acc[a][c][oc] = 0.f;

  C1_LOAD(0);
  C1_WRITE(0);
  __syncthreads();
  int cur = 0;

#pragma unroll 1
  for (int ic = 0; ic < 4; ++ic) {
    if (ic < 3) C1_LOAD(ic + 1);
    const float* __restrict__ sc = sIn[cur];
#pragma unroll 1
    for (int dy = 0; dy < 7; ++dy) {
      float v[2][8];
#pragma unroll
      for (int a = 0; a < 2; ++a) {
        const int base = k * C1_PS + (2 * pyl + a + dy) * C1_RS + 2 * pxl;
#pragma unroll
        for (int j = 0; j < 4; ++j) {
          float2 f = *reinterpret_cast<const float2*>(&sc[base + 2 * j]);
          v[a][2 * j] = f.x;
          v[a][2 * j + 1] = f.y;
        }
      }
      const float* __restrict__ wd = wt1 + ic * 392 + dy * 56;   // uniform -> s_load
#pragma unroll
      for (int dx = 0; dx < 7; ++dx) {
#pragma unroll
        for (int a = 0; a < 2; ++a)
#pragma unroll
          for (int c = 0; c < 2; ++c) {
            const float val = v[a][c + dx];
#pragma unroll
            for (int oc = 0; oc < 8; ++oc)
              acc[a][c][oc] = fmaf(val, wd[dx * 8 + oc], acc[a][c][oc]);
          }
      }
    }
    if (ic < 3) {
      C1_WRITE(cur ^ 1);
      __syncthreads();
      cur ^= 1;
    }
  }
#undef C1_LOAD
#undef C1_WRITE

  const int py = ty * 4 + pyl, px = tx * 4 + pxl;
  if (py < 125 && px < 125) {
#pragma unroll
    for (int oc = 0; oc < 8; ++oc) {
      float m = fmaxf(fmaxf(acc[0][0][oc], acc[0][1][oc]),
                      fmaxf(acc[1][0][oc], acc[1][1][oc])) + b1[oc];
      buf1[(((b * 8 + oc) * 125 + py) * 125 + px) * 16 + k] = fmaxf(m, 0.f);
    }
  }
}

// ================= conv2 (5x5x1, 8->10) + pool + relu =================
#define C2_RS 16
#define C2_PS 194
__global__ __launch_bounds__(256) void k_conv2(const float* __restrict__ in,
                                               const float* __restrict__ wt2,
                                               const float* __restrict__ b2,
                                               float* __restrict__ buf2) {
  __shared__ float sIn[2][16 * C2_PS];
  const int tid = threadIdx.x;
  const int tx = blockIdx.x, ty = blockIdx.y, b = blockIdx.z;

  const int k = tid & 15;
  const int pix = tid >> 4;
  const int pyl = pix >> 2, pxl = pix & 3;
  const int row0 = ty * 8, col0 = tx * 8;

  int sq[3], srow[3], scol[3], sbase[3];
#pragma unroll
  for (int it = 0; it < 3; ++it) {
    int t = tid + it * 256;
    int q = t & 3, pos = t >> 2;
    int coli = pos % 12, rowi = pos / 12;
    sq[it] = q;
    srow[it] = row0 + rowi;
    scol[it] = col0 + coli;
    sbase[it] = rowi * C2_RS + coli;
  }

  const float4* __restrict__ in4 = reinterpret_cast<const float4*>(in);
  float4 st[3];

#define C2_LOAD(ICV) do {                                                    \
  _Pragma("unroll")                                                          \
  for (int it = 0; it < 3; ++it) {                                           \
    if (it < 2 || tid < 64)                                                  \
      st[it] = in4[(((b * 8 + (ICV)) * 125 + srow[it]) * 125 + scol[it]) * 4 + sq[it]]; \
  } } while (0)

#define C2_WRITE(S) do {                                                     \
  _Pragma("unroll")                                                          \
  for (int it = 0; it < 3; ++it) {                                           \
    if (it < 2 || tid < 64) {                                                \
      float* sp = &sIn[S][(4 * sq[it]) * C2_PS + sbase[it]];                 \
      sp[0 * C2_PS] = st[it].x;                                              \
      sp[1 * C2_PS] = st[it].y;                                              \
      sp[2 * C2_PS] = st[it].z;                                              \
      sp[3 * C2_PS] = st[it].w;                                              \
    }                                                                        \
  } } while (0)

  float acc[2][2][10];
#pragma unroll
  for (int a = 0; a < 2; ++a)
#pragma unroll
    for (int c = 0; c < 2; ++c)
#pragma unroll
      for (int oc = 0; oc < 10; ++oc) acc[a][c][oc] = 0.f;

  C2_LOAD(0);
  C2_WRITE(0);
  __syncthreads();
  int cur = 0;

#pragma unroll 1
  for (int ic = 0; ic < 8; ++ic) {
    if (ic < 7) C2_LOAD(ic + 1);
    const float* __restrict__ sc = sIn[cur];
#pragma unroll 1
    for (int dy = 0; dy < 5; ++dy) {
      float v[2][6];
#pragma unroll
      for (int a = 0; a < 2; ++a) {
        const int base = k * C2_PS + (2 * pyl + a + dy) * C2_RS + 2 * pxl;
#pragma unroll
        for (int j = 0; j < 3; ++j) {
          float2 f = *reinterpret_cast<const float2*>(&sc[base + 2 * j]);
          v[a][2 * j] = f.x;
          v[a][2 * j + 1] = f.y;
        }
      }
      const float* __restrict__ wd = wt2 + ic * 250 + dy * 50;   // uniform -> s_load
#pragma unroll
      for (int dx = 0; dx < 5; ++dx) {
#pragma unroll
        for (int a = 0; a < 2; ++a)
#pragma unroll
          for (int c = 0; c < 2; ++c) {
            const float val = v[a][c + dx];
#pragma unroll
            for (int oc = 0; oc < 10; ++oc)
              acc[a][c][oc] = fmaf(val, wd[dx * 10 + oc], acc[a][c][oc]);
          }
      }
    }
    if (ic < 7) {
      C2_WRITE(cur ^ 1);
      __syncthreads();
      cur ^= 1;
    }
  }
#undef C2_LOAD
#undef C2_WRITE

  const int py = ty * 4 + pyl, px = tx * 4 + pxl;
#pragma unroll
  for (int oc = 0; oc < 10; ++oc) {
    float m = fmaxf(fmaxf(acc[0][0][oc], acc[0][1][oc]),
                    fmaxf(acc[1][0][oc], acc[1][1][oc])) + b2[oc];
    buf2[(((b * 10 + oc) * 60 + py) * 60 + px) * 16 + k] = fmaxf(m, 0.f);
  }
}

// ================= fc1 split-K pass 1: partial[2000][256], float4 loads =================
__global__ __launch_bounds__(256) void k_fc1(const float* __restrict__ z,
                                             const float* __restrict__ w,
                                             float* __restrict__ partial) {
  const int bid = blockIdx.x, tid = threadIdx.x;
  const int b = tid >> 5, o = tid & 31;
  const int k0 = bid * 288;                 // 2000 * 288 == 576000
  const float4* __restrict__ zp = reinterpret_cast<const float4*>(z + b * FC1_K + k0);
  const float4* __restrict__ wp = reinterpret_cast<const float4*>(w + o * FC1_K + k0);
  float a0 = 0.f, a1 = 0.f, a2 = 0.f, a3 = 0.f;
  float a4 = 0.f, a5 = 0.f, a6 = 0.f, a7 = 0.f;
#pragma unroll 2
  for (int i = 0; i < 72; i += 2) {
    float4 z0 = zp[i], w0 = wp[i];
    float4 z1 = zp[i + 1], w1 = wp[i + 1];
    a0 = fmaf(z0.x, w0.x, a0);
    a1 = fmaf(z0.y, w0.y, a1);
    a2 = fmaf(z0.z, w0.z, a2);
    a3 = fmaf(z0.w, w0.w, a3);
    a4 = fmaf(z1.x, w1.x, a4);
    a5 = fmaf(z1.y, w1.y, a5);
    a6 = fmaf(z1.z, w1.z, a6);
    a7 = fmaf(z1.w, w1.w, a7);
  }
  partial[bid * 256 + tid] = ((a0 + a1) + (a2 + a3)) + ((a4 + a5) + (a6 + a7));
}

// ======== red: partial[2000][256] -> red[80][256] ========
__global__ __launch_bounds__(256) void k_red(const float* __restrict__ partial,
                                             float* __restrict__ red) {
  const int bl = blockIdx.x, tid = threadIdx.x;
  const float* __restrict__ p = partial + bl * 25 * 256 + tid;
  float s0 = 0.f, s1 = 0.f, s2 = 0.f, s3 = 0.f, s4 = 0.f;
#pragma unroll
  for (int i = 0; i < 25; i += 5) {
    s0 += p[i * 256];
    s1 += p[(i + 1) * 256];
    s2 += p[(i + 2) * 256];
    s3 += p[(i + 3) * 256];
    s4 += p[(i + 4) * 256];
  }
  red[bl * 256 + tid] = ((s0 + s1) + (s2 + s3)) + s4;
}

// ======== head: reduce red[80][256] -> fc1 relu -> fc2 tanh -> R, Tv ========
__global__ __launch_bounds__(256) void k_head(const float* __restrict__ red,
                                              const float* __restrict__ fc1_b,
                                              const float* __restrict__ fc2_w,
                                              const float* __restrict__ fc2_b,
                                              float* __restrict__ RT) {
  __shared__ float sH[256];
  __shared__ float sTh[8][24];
  const int tid = threadIdx.x;
  float s0 = 0.f, s1 = 0.f, s2 = 0.f, s3 = 0.f;
#pragma unroll
  for (int c = 0; c < 80; c += 4) {
    s0 += red[c * 256 + tid];
    s1 += red[(c + 1) * 256 + tid];
    s2 += red[(c + 2) * 256 + tid];
    s3 += red[(c + 3) * 256 + tid];
  }
  const int o = tid & 31;
  sH[tid] = fmaxf(((s0 + s1) + (s2 + s3)) + fc1_b[o], 0.f);
  __syncthreads();
  if (tid < 192) {
    int b = tid / 24, o2 = tid % 24;
    float a = fc2_b[o2];
#pragma unroll
    for (int i = 0; i < 32; ++i) a = fmaf(sH[b * 32 + i], fc2_w[o2 * 32 + i], a);
    sTh[b][o2] = tanhf(a);
  }
  __syncthreads();
  if (tid < 32) {
    const int b = tid >> 2, t = tid & 3;
    const float PI = 3.14159265358979323846f;
    float a0 = PI * sTh[b][t * 6 + 0];
    float a1 = PI * sTh[b][t * 6 + 1];
    float a2 = PI * sTh[b][t * 6 + 2];
    float t0 = sTh[b][t * 6 + 3], t1 = sTh[b][t * 6 + 4], t2 = sTh[b][t * 6 + 5];
    float c0 = cosf(a0), s0v = sinf(a0);
    float c1 = cosf(a1), s1v = sinf(a1);
    float c2 = cosf(a2), s2v = sinf(a2);
    float R[3][3];
    R[0][0] = c0 * c1;
    R[0][1] = c0 * s1v * s2v - s0v * c2;
    R[0][2] = c0 * s1v * c2 + s0v * s2v;
    R[1][0] = s0v * c1;
    R[1][1] = s0v * s1v * s2v + c0 * c2;
    R[1][2] = s0v * s1v * c2 - c0 * s2v;
    R[2][0] = -s1v;
    R[2][1] = c1 * s2v;
    R[2][2] = c1 * c2;
    const float SZv[3] = {256.f, 256.f, 16.f};
    const float cen[3] = {128.f, 128.f, 8.f};
    const float tr[3] = {t0, t1, t2};
    float* rt = RT + (b * 4 + t) * 12;
#pragma unroll
    for (int kq = 0; kq < 3; ++kq)
#pragma unroll
      for (int s = 0; s < 3; ++s) rt[kq * 3 + s] = R[kq][s];
#pragma unroll
    for (int s = 0; s < 3; ++s)
      rt[9 + s] = tr[s] * SZv[s] + cen[s] - (128.f * R[0][s] + 128.f * R[1][s] + 8.f * R[2][s]);
  }
}

// ====== flow + grid_out + trilinear grid-sample -> X_t ======
// R13: halve gather VMEM instructions. The x-interp pair (cx0,cx0+1) is
// contiguous (k innermost) -> one float2 row-pair load per (z,y) row: 16 loads
// per thread vs 32. Limiter model (R8-R12 elimination): per-VMEM-instruction
// address-processing cost (~25 cyc/instr), NOT latency/BW/stores/occupancy.
__global__ __launch_bounds__(256) void k_flow(const float* __restrict__ x,
                                              const float* __restrict__ RT,
                                              float* __restrict__ out) {
  const int raw = blockIdx.x;
  const int bid = (raw & 7) * 4096 + (raw >> 3);   // XCD-contiguous chunk
  const int tid = threadIdx.x;
  const int b = bid >> 12;
  const int l = ((bid & 4095) << 8) | tid;
  const int i = l >> 12, j = (l >> 4) & 255, k = l & 15;
  const float fi = (float)i, fj = (float)j, fk = (float)k;
  const float* __restrict__ rt = RT + b * 48;

  const float txs[4] = {64.f, 64.f, 192.f, 192.f};
  const float tys[4] = {64.f, 192.f, 64.f, 192.f};
  float e[4], es = 0.f;
#pragma unroll
  for (int t = 0; t < 4; ++t) {
    float dx = fi - txs[t], dy = fj - tys[t], dz = fk - 8.f;
    float d = __builtin_amdgcn_sqrtf(fmaf(dx, dx, fmaf(dy, dy, dz * dz)));
    e[t] = __expf(-0.1f * d);
    es += e[t];
  }
  float inv = __builtin_amdgcn_rcpf(es);
  float f0 = 0.f, f1 = 0.f, f2 = 0.f;
#pragma unroll
  for (int t = 0; t < 4; ++t) {
    float wt = e[t] * inv;
    const float* r = rt + t * 12;
    f0 += wt * (fi * r[0] + fj * r[3] + fk * r[6] + r[9]);
    f1 += wt * (fi * r[1] + fj * r[4] + fk * r[7] + r[10]);
    f2 += wt * (fi * r[2] + fj * r[5] + fk * r[8] + r[11]);
  }
  float nf0 = f0 * (1.f / 128.f) - 1.f;
  float nf1 = f1 * (1.f / 128.f) - 1.f;
  float nf2 = f2 * 0.125f - 1.f;

  int gbase = OUT_GRID + ((b << 20) + l) * 3;
  __builtin_nontemporal_store(nf2, &out[gbase]);
  __builtin_nontemporal_store(nf1, &out[gbase + 1]);
  __builtin_nontemporal_store(nf0, &out[gbase + 2]);

  float ix = ((nf2 + 1.f) * 16.f - 1.f) * 0.5f;
  float iy = ((nf1 + 1.f) * 256.f - 1.f) * 0.5f;
  float iz = ((nf0 + 1.f) * 256.f - 1.f) * 0.5f;
  float xf = floorf(ix), yf = floorf(iy), zf = floorf(iz);
  float fx = ix - xf, fy = iy - yf, fz = iz - zf;
  int x0 = (int)xf, y0 = (int)yf, z0 = (int)zf;
  int x1 = x0 + 1, y1 = y0 + 1, z1 = z0 + 1;
  bool vx0 = ((unsigned)x0 < 16u), vx1 = ((unsigned)x1 < 16u);
  bool vy0 = ((unsigned)y0 < 256u), vy1 = ((unsigned)y1 < 256u);
  bool vz0 = ((unsigned)z0 < 256u), vz1 = ((unsigned)z1 < 256u);
  int cx0 = min(max(x0, 0), 15), cx1 = min(max(x1, 0), 15);
  int cy0 = min(max(y0, 0), 255), cy1 = min(max(y1, 0), 255);
  int cz0 = min(max(z0, 0), 255), cz1 = min(max(z1, 0), 255);
  float wx0 = 1.f - fx, wx1 = fx, wy0 = 1.f - fy, wy1 = fy, wz0 = 1.f - fz, wz1 = fz;

  // x-pair coefficients: value_row = ca*f.x + cb*f.y  (f = float2 at base_x)
  const float wxa = vx0 ? wx0 : 0.f;
  const float wxb = vx1 ? wx1 : 0.f;
  const int base_x = min(cx0, 14);
  const int i0 = cx0 - base_x;   // 0 or 1
  const int i1 = cx1 - base_x;   // 0 or 1
  const float ca = (i0 ? 0.f : wxa) + (i1 ? 0.f : wxb);
  const float cb = (i0 ? wxa : 0.f) + (i1 ? wxb : 0.f);

  float W4[4];
  W4[0] = wz0 * wy0 * ((vz0 && vy0) ? 1.f : 0.f);
  W4[1] = wz0 * wy1 * ((vz0 && vy1) ? 1.f : 0.f);
  W4[2] = wz1 * wy0 * ((vz1 && vy0) ? 1.f : 0.f);
  W4[3] = wz1 * wy1 * ((vz1 && vy1) ? 1.f : 0.f);

  int ro[4];
  ro[0] = (cz0 << 12) + (cy0 << 4) + base_x;
  ro[1] = (cz0 << 12) + (cy1 << 4) + base_x;
  ro[2] = (cz1 << 12) + (cy0 << 4) + base_x;
  ro[3] = (cz1 << 12) + (cy1 << 4) + base_x;

  const float* __restrict__ xb0 = x + ((size_t)(b * 4) << 20);

  // channels 0,1: 8 row-pair loads in flight
  {
    float2 fa[4], fb[4];
#pragma unroll
    for (int q = 0; q < 4; ++q) __builtin_memcpy(&fa[q], xb0 + ro[q], 8);
#pragma unroll
    for (int q = 0; q < 4; ++q) __builtin_memcpy(&fb[q], xb0 + (1 << 20) + ro[q], 8);
    float s0 = 0.f, s1 = 0.f;
#pragma unroll
    for (int q = 0; q < 4; ++q) {
      s0 = fmaf(W4[q], fmaf(cb, fa[q].y, ca * fa[q].x), s0);
      s1 = fmaf(W4[q], fmaf(cb, fb[q].y, ca * fb[q].x), s1);
    }
    __builtin_nontemporal_store(s0, &out[OUT_XT + ((b * 4 + 0) << 20) + l]);
    __builtin_nontemporal_store(s1, &out[OUT_XT + ((b * 4 + 1) << 20) + l]);
  }
  // channels 2,3
  {
    float2 fa[4], fb[4];
#pragma unroll
    for (int q = 0; q < 4; ++q) __builtin_memcpy(&fa[q], xb0 + (2 << 20) + ro[q], 8);
#pragma unroll
    for (int q = 0; q < 4; ++q) __builtin_memcpy(&fb[q], xb0 + (3 << 20) + ro[q], 8);
    float s0 = 0.f, s1 = 0.f;
#pragma unroll
    for (int q = 0; q < 4; ++q) {
      s0 = fmaf(W4[q], fmaf(cb, fa[q].y, ca * fa[q].x), s0);
      s1 = fmaf(W4[q], fmaf(cb, fb[q].y, ca * fb[q].x), s1);
    }
    __builtin_nontemporal_store(s0, &out[OUT_XT + ((b * 4 + 2) << 20) + l]);
    __builtin_nontemporal_store(s1, &out[OUT_XT + ((b * 4 + 3) << 20) + l]);
  }
}

// ====== moved + reg ======
__global__ __launch_bounds__(256) void k_tail(const float* __restrict__ P,
                                              const float* __restrict__ centers,
                                              const int* __restrict__ times,
                                              float* __restrict__ out) {
  const int b = blockIdx.x, tid = threadIdx.x;
  __shared__ float sred[256];
  float nrm = 0.f;
  if (tid < 200) {
    int tb = times[b];
    float p0 = P[tid * 96 + tb];
    float p1 = P[tid * 96 + 32 + tb];
    float p2 = P[tid * 96 + 64 + tb];
    int i0 = (int)rintf(p0), i1 = (int)rintf(p1), i2 = (int)rintf(p2);
    int lp = (i0 << 12) + (i1 << 4) + i2;
    int gb = OUT_GRID + ((b << 20) + lp) * 3;
    float a0 = out[gb + 2];
    float a1 = out[gb + 1];
    float a2 = out[gb + 0];
    float m0 = 2.f * p0 - (0.5f + 0.5f * a0) * 255.f;
    float m1 = 2.f * p1 - (0.5f + 0.5f * a1) * 255.f;
    float m2 = 2.f * p2 - (0.5f + 0.5f * a2) * 15.f;
    int mo = OUT_MOVED + (b * 200 + tid) * 3;
    out[mo] = m0;
    out[mo + 1] = m1;
    out[mo + 2] = m2;
    float d0 = m0 - centers[tid * 3];
    float d1 = m1 - centers[tid * 3 + 1];
    float d2 = m2 - centers[tid * 3 + 2];
    nrm = sqrtf(d0 * d0 + d1 * d1 + d2 * d2);
  }
  sred[tid] = nrm;
  __syncthreads();
  for (int s = 128; s > 0; s >>= 1) {
    if (tid < s) sred[tid] += sred[tid + s];
    __syncthreads();
  }
  if (tid == 0) out[OUT_REG + b] = sred[0] * 0.005f;
}

extern "C" void kernel_launch(void* const* d_in, const int* in_sizes, int n_in,
                              void* d_out, int out_size, void* d_ws, size_t ws_size,
                              hipStream_t stream) {
  const float* x = (const float*)d_in[0];
  const int* times = (const int*)d_in[1];
  const float* w1 = (const float*)d_in[2];
  const float* b1 = (const float*)d_in[3];
  const float* w2 = (const float*)d_in[4];
  const float* b2 = (const float*)d_in[5];
  const float* fw1 = (const float*)d_in[6];
  const float* fb1 = (const float*)d_in[7];
  const float* fw2 = (const float*)d_in[8];
  const float* fb2 = (const float*)d_in[9];
  const float* P = (const float*)d_in[10];
  const float* centers = (const float*)d_in[11];
  float* out = (float*)d_out;

  float* wt1 = (float*)d_ws;          // 1568 floats
  float* wt2 = wt1 + 1568;            // 2000 floats

  float* buf1 = out + WS_BUF1;
  float* buf2 = out + WS_BUF2;
  float* partial = out + WS_PART;
  float* red = out + WS_RED;
  float* RT = out + WS_RT;

  k_prep<<<1, 256, 0, stream>>>(w1, w2, wt1, wt2);
  for (int zb = 0; zb < 8; zb += 4)
    k_conv1<<<dim3(32, 32, 4), 256, 0, stream>>>(x, wt1, b1, buf1, zb);
  k_conv2<<<dim3(15, 15, 8), 256, 0, stream>>>(buf1, wt2, b2, buf2);
  k_fc1<<<2000, 256, 0, stream>>>(buf2, fw1, partial);
  k_red<<<80, 256, 0, stream>>>(partial, red);
  k_head<<<1, 256, 0, stream>>>(red, fb1, fw2, fb2, RT);
  k_flow<<<32768, 256, 0, stream>>>(x, RT, out);
  k_tail<<<8, 256, 0, stream>>>(P, centers, times, out);
}

// Round 14
// 509.681 us; speedup vs baseline: 1.2138x; 1.0249x over previous
//
#include <hip/hip_runtime.h>
#include <math.h>

// ---- problem constants ----
#define OUT_XT     0
#define OUT_GRID   33554432
#define OUT_REG    58720256
#define OUT_MOVED  58720264
#define FC1_K      576000

// scratch inside d_out (regions consumed before being overwritten):
#define WS_BUF1    0          // (8,8,125,125,16) -- inside X_t region
#define WS_BUF2    16000000   // (8,10,60,60,16)
#define WS_PART    20608000   // 2000 x 256
#define WS_RED     21120000   // 80 x 256
#define WS_RT      58720256   // 8x4x12 -- reg+moved region, overwritten by k_tail

// ======== prep: transpose weights into [ic][dd][oc] for contiguous uniform (s_load) reads ========
__global__ __launch_bounds__(256) void k_prep(const float* __restrict__ w1,
                                              const float* __restrict__ w2,
                                              float* __restrict__ wt1,
                                              float* __restrict__ wt2) {
  const int tid = threadIdx.x;
  for (int t = tid; t < 1568; t += 256) {
    int oc = t & 7, idx = t >> 3;
    int ic = idx / 49, dd = idx % 49;
    wt1[t] = w1[(oc * 4 + ic) * 49 + dd];
  }
  for (int t = tid; t < 2000; t += 256) {
    int oc = t % 10, idx = t / 10;
    int ic = idx / 25, dd = idx % 25;
    wt2[t] = w2[(oc * 8 + ic) * 25 + dd];
  }
}

// ================= conv1 (7x7x1, 4->8) + pool(2,2,1) + relu =================
// R14 wide tile: 4x8 pooled per block (8x16 conv, 14x22 input), 2 pooled cols
// per thread -> 44.8 FMA per ds_read_b64 (was 28), halo overfetch 1.93x (was
// 3.06x). LDS [k][row][col], plane 322 == 2 mod 32: read bank = 2k+4pxl+const
// covers every even residue exactly 4x = conflict-free b64 minimum.
#define C1_RS 22
#define C1_PS 322
__global__ __launch_bounds__(256) void k_conv1(const float* __restrict__ x,
                                               const float* __restrict__ wt1,
                                               const float* __restrict__ b1,
                                               float* __restrict__ buf1,
                                               int zbase) {
  __shared__ float sIn[2][16 * C1_PS];
  const int tid = threadIdx.x;
  const int tx = blockIdx.x, ty = blockIdx.y, b = blockIdx.z + zbase;

  const int k = tid & 15;
  const int pix = tid >> 4;
  const int pyl = pix >> 2, pxl = pix & 3;
  const int row0 = ty * 8, col0 = tx * 16;

  // staging geometry: 14x22 positions x 4 float4 = 1232 loads, 5 slots
  int sq[5], srow[5], scol[5], sbase[5];
  bool sval[5];
#pragma unroll
  for (int it = 0; it < 5; ++it) {
    int t = tid + it * 256;
    int q = t & 3, pos = t >> 2;
    int coli = pos % 22, rowi = pos / 22;
    sq[it] = q;
    srow[it] = row0 + rowi;
    scol[it] = col0 + coli;
    sbase[it] = rowi * C1_RS + coli;
    sval[it] = (t < 1232) && (srow[it] < 256) && (scol[it] < 256);
  }

  const float4* __restrict__ x4 = reinterpret_cast<const float4*>(x);
  float4 st[5];

#define C1_LOAD(ICV) do {                                                    \
  _Pragma("unroll")                                                          \
  for (int it = 0; it < 5; ++it) {                                           \
    float4 v = make_float4(0.f, 0.f, 0.f, 0.f);                              \
    if (sval[it])                                                            \
      v = x4[(((b * 4 + (ICV)) * 256 + srow[it]) * 256 + scol[it]) * 4 + sq[it]]; \
    st[it] = v;                                                              \
  } } while (0)

#define C1_WRITE(S) do {                                                     \
  _Pragma("unroll")                                                          \
  for (int it = 0; it < 5; ++it) {                                           \
    if (it < 4 || tid < 208) {                                               \
      float* sp = &sIn[S][(4 * sq[it]) * C1_PS + sbase[it]];                 \
      sp[0 * C1_PS] = st[it].x;                                              \
      sp[1 * C1_PS] = st[it].y;                                              \
      sp[2 * C1_PS] = st[it].z;                                              \
      sp[3 * C1_PS] = st[it].w;                                              \
    }                                                                        \
  } } while (0)

  float acc[2][4][8];
#pragma unroll
  for (int a = 0; a < 2; ++a)
#pragma unroll
    for (int c = 0; c < 4; ++c)
#pragma unroll
      for (int oc = 0; oc < 8; ++oc) acc[a][c][oc] = 0.f;

  C1_LOAD(0);
  C1_WRITE(0);
  __syncthreads();
  int cur = 0;

#pragma unroll 1
  for (int ic = 0; ic < 4; ++ic) {
    if (ic < 3) C1_LOAD(ic + 1);        // T14: global latency hides under compute
    const float* __restrict__ sc = sIn[cur];
#pragma unroll 1
    for (int dy = 0; dy < 7; ++dy) {
      float v[2][10];
#pragma unroll
      for (int a = 0; a < 2; ++a) {
        const int base = k * C1_PS + (2 * pyl + a + dy) * C1_RS + 4 * pxl;
#pragma unroll
        for (int j = 0; j < 5; ++j) {
          float2 f = *reinterpret_cast<const float2*>(&sc[base + 2 * j]);
          v[a][2 * j] = f.x;
          v[a][2 * j + 1] = f.y;
        }
      }
      const float* __restrict__ wd = wt1 + ic * 392 + dy * 56;   // uniform -> s_load
#pragma unroll
      for (int dx = 0; dx < 7; ++dx) {
#pragma unroll
        for (int a = 0; a < 2; ++a)
#pragma unroll
          for (int c = 0; c < 4; ++c) {
            const float val = v[a][c + dx];
#pragma unroll
            for (int oc = 0; oc < 8; ++oc)
              acc[a][c][oc] = fmaf(val, wd[dx * 8 + oc], acc[a][c][oc]);
          }
      }
    }
    if (ic < 3) {
      C1_WRITE(cur ^ 1);
      __syncthreads();
      cur ^= 1;
    }
  }
#undef C1_LOAD
#undef C1_WRITE

  const int py = ty * 4 + pyl;
  if (py < 125) {
#pragma unroll
    for (int cc = 0; cc < 2; ++cc) {
      const int px = tx * 8 + 2 * pxl + cc;
      if (px < 125) {
#pragma unroll
        for (int oc = 0; oc < 8; ++oc) {
          float m = fmaxf(fmaxf(acc[0][2 * cc][oc], acc[0][2 * cc + 1][oc]),
                          fmaxf(acc[1][2 * cc][oc], acc[1][2 * cc + 1][oc])) + b1[oc];
          buf1[(((b * 8 + oc) * 125 + py) * 125 + px) * 16 + k] = fmaxf(m, 0.f);
        }
      }
    }
  }
}

// ================= conv2 (5x5x1, 8->10) + pool + relu =================
// Wide tile: 4x8 pooled per block (8x16 conv, 12x20 input), 2 pooled cols/thread.
#define C2_RS 20
#define C2_PS 258
__global__ __launch_bounds__(256) void k_conv2(const float* __restrict__ in,
                                               const float* __restrict__ wt2,
                                               const float* __restrict__ b2,
                                               float* __restrict__ buf2) {
  __shared__ float sIn[2][16 * C2_PS];
  const int tid = threadIdx.x;
  const int tx = blockIdx.x, ty = blockIdx.y, b = blockIdx.z;

  const int k = tid & 15;
  const int pix = tid >> 4;
  const int pyl = pix >> 2, pxl = pix & 3;
  const int row0 = ty * 8, col0 = tx * 16;

  // staging: 12x20 positions x 4 = 960 loads, 4 slots
  int sq[4], srow[4], scol[4], sbase[4];
  bool sval[4];
#pragma unroll
  for (int it = 0; it < 4; ++it) {
    int t = tid + it * 256;
    int q = t & 3, pos = t >> 2;
    int coli = pos % 20, rowi = pos / 20;
    sq[it] = q;
    srow[it] = row0 + rowi;                 // <= 123, always in-bounds
    scol[it] = col0 + coli;
    sbase[it] = rowi * C2_RS + coli;
    sval[it] = (t < 960) && (scol[it] < 125);
  }

  const float4* __restrict__ in4 = reinterpret_cast<const float4*>(in);
  float4 st[4];

#define C2_LOAD(ICV) do {                                                    \
  _Pragma("unroll")                                                          \
  for (int it = 0; it < 4; ++it) {                                           \
    float4 v = make_float4(0.f, 0.f, 0.f, 0.f);                              \
    if (sval[it])                                                            \
      v = in4[(((b * 8 + (ICV)) * 125 + srow[it]) * 125 + scol[it]) * 4 + sq[it]]; \
    st[it] = v;                                                              \
  } } while (0)

#define C2_WRITE(S) do {                                                     \
  _Pragma("unroll")                                                          \
  for (int it = 0; it < 4; ++it) {                                           \
    if (it < 3 || tid < 192) {                                               \
      float* sp = &sIn[S][(4 * sq[it]) * C2_PS + sbase[it]];                 \
      sp[0 * C2_PS] = st[it].x;                                              \
      sp[1 * C2_PS] = st[it].y;                                              \
      sp[2 * C2_PS] = st[it].z;                                              \
      sp[3 * C2_PS] = st[it].w;                                              \
    }                                                                        \
  } } while (0)

  float acc[2][4][10];
#pragma unroll
  for (int a = 0; a < 2; ++a)
#pragma unroll
    for (int c = 0; c < 4; ++c)
#pragma unroll
      for (int oc = 0; oc < 10; ++oc) acc[a][c][oc] = 0.f;

  C2_LOAD(0);
  C2_WRITE(0);
  __syncthreads();
  int cur = 0;

#pragma unroll 1
  for (int ic = 0; ic < 8; ++ic) {
    if (ic < 7) C2_LOAD(ic + 1);
    const float* __restrict__ sc = sIn[cur];
#pragma unroll 1
    for (int dy = 0; dy < 5; ++dy) {
      float v[2][8];
#pragma unroll
      for (int a = 0; a < 2; ++a) {
        const int base = k * C2_PS + (2 * pyl + a + dy) * C2_RS + 4 * pxl;
#pragma unroll
        for (int j = 0; j < 4; ++j) {
          float2 f = *reinterpret_cast<const float2*>(&sc[base + 2 * j]);
          v[a][2 * j] = f.x;
          v[a][2 * j + 1] = f.y;
        }
      }
      const float* __restrict__ wd = wt2 + ic * 250 + dy * 50;   // uniform -> s_load
#pragma unroll
      for (int dx = 0; dx < 5; ++dx) {
#pragma unroll
        for (int a = 0; a < 2; ++a)
#pragma unroll
          for (int c = 0; c < 4; ++c) {
            const float val = v[a][c + dx];
#pragma unroll
            for (int oc = 0; oc < 10; ++oc)
              acc[a][c][oc] = fmaf(val, wd[dx * 10 + oc], acc[a][c][oc]);
          }
      }
    }
    if (ic < 7) {
      C2_WRITE(cur ^ 1);
      __syncthreads();
      cur ^= 1;
    }
  }
#undef C2_LOAD
#undef C2_WRITE

  const int py = ty * 4 + pyl;        // <= 59, always valid
#pragma unroll
  for (int cc = 0; cc < 2; ++cc) {
    const int px = tx * 8 + 2 * pxl + cc;
    if (px < 60) {
#pragma unroll
      for (int oc = 0; oc < 10; ++oc) {
        float m = fmaxf(fmaxf(acc[0][2 * cc][oc], acc[0][2 * cc + 1][oc]),
                        fmaxf(acc[1][2 * cc][oc], acc[1][2 * cc + 1][oc])) + b2[oc];
        buf2[(((b * 10 + oc) * 60 + py) * 60 + px) * 16 + k] = fmaxf(m, 0.f);
      }
    }
  }
}

// ================= fc1 split-K pass 1: partial[2000][256], float4 loads =================
__global__ __launch_bounds__(256) void k_fc1(const float* __restrict__ z,
                                             const float* __restrict__ w,
                                             float* __restrict__ partial) {
  const int bid = blockIdx.x, tid = threadIdx.x;
  const int b = tid >> 5, o = tid & 31;
  const int k0 = bid * 288;                 // 2000 * 288 == 576000
  const float4* __restrict__ zp = reinterpret_cast<const float4*>(z + b * FC1_K + k0);
  const float4* __restrict__ wp = reinterpret_cast<const float4*>(w + o * FC1_K + k0);
  float a0 = 0.f, a1 = 0.f, a2 = 0.f, a3 = 0.f;
  float a4 = 0.f, a5 = 0.f, a6 = 0.f, a7 = 0.f;
#pragma unroll 2
  for (int i = 0; i < 72; i += 2) {
    float4 z0 = zp[i], w0 = wp[i];
    float4 z1 = zp[i + 1], w1 = wp[i + 1];
    a0 = fmaf(z0.x, w0.x, a0);
    a1 = fmaf(z0.y, w0.y, a1);
    a2 = fmaf(z0.z, w0.z, a2);
    a3 = fmaf(z0.w, w0.w, a3);
    a4 = fmaf(z1.x, w1.x, a4);
    a5 = fmaf(z1.y, w1.y, a5);
    a6 = fmaf(z1.z, w1.z, a6);
    a7 = fmaf(z1.w, w1.w, a7);
  }
  partial[bid * 256 + tid] = ((a0 + a1) + (a2 + a3)) + ((a4 + a5) + (a6 + a7));
}

// ======== red: partial[2000][256] -> red[80][256] ========
__global__ __launch_bounds__(256) void k_red(const float* __restrict__ partial,
                                             float* __restrict__ red) {
  const int bl = blockIdx.x, tid = threadIdx.x;
  const float* __restrict__ p = partial + bl * 25 * 256 + tid;
  float s0 = 0.f, s1 = 0.f, s2 = 0.f, s3 = 0.f, s4 = 0.f;
#pragma unroll
  for (int i = 0; i < 25; i += 5) {
    s0 += p[i * 256];
    s1 += p[(i + 1) * 256];
    s2 += p[(i + 2) * 256];
    s3 += p[(i + 3) * 256];
    s4 += p[(i + 4) * 256];
  }
  red[bl * 256 + tid] = ((s0 + s1) + (s2 + s3)) + s4;
}

// ======== head: reduce red[80][256] -> fc1 relu -> fc2 tanh -> R, Tv ========
__global__ __launch_bounds__(256) void k_head(const float* __restrict__ red,
                                              const float* __restrict__ fc1_b,
                                              const float* __restrict__ fc2_w,
                                              const float* __restrict__ fc2_b,
                                              float* __restrict__ RT) {
  __shared__ float sH[256];
  __shared__ float sTh[8][24];
  const int tid = threadIdx.x;
  float s0 = 0.f, s1 = 0.f, s2 = 0.f, s3 = 0.f;
#pragma unroll
  for (int c = 0; c < 80; c += 4) {
    s0 += red[c * 256 + tid];
    s1 += red[(c + 1) * 256 + tid];
    s2 += red[(c + 2) * 256 + tid];
    s3 += red[(c + 3) * 256 + tid];
  }
  const int o = tid & 31;
  sH[tid] = fmaxf(((s0 + s1) + (s2 + s3)) + fc1_b[o], 0.f);
  __syncthreads();
  if (tid < 192) {
    int b = tid / 24, o2 = tid % 24;
    float a = fc2_b[o2];
#pragma unroll
    for (int i = 0; i < 32; ++i) a = fmaf(sH[b * 32 + i], fc2_w[o2 * 32 + i], a);
    sTh[b][o2] = tanhf(a);
  }
  __syncthreads();
  if (tid < 32) {
    const int b = tid >> 2, t = tid & 3;
    const float PI = 3.14159265358979323846f;
    float a0 = PI * sTh[b][t * 6 + 0];
    float a1 = PI * sTh[b][t * 6 + 1];
    float a2 = PI * sTh[b][t * 6 + 2];
    float t0 = sTh[b][t * 6 + 3], t1 = sTh[b][t * 6 + 4], t2 = sTh[b][t * 6 + 5];
    float c0 = cosf(a0), s0v = sinf(a0);
    float c1 = cosf(a1), s1v = sinf(a1);
    float c2 = cosf(a2), s2v = sinf(a2);
    float R[3][3];
    R[0][0] = c0 * c1;
    R[0][1] = c0 * s1v * s2v - s0v * c2;
    R[0][2] = c0 * s1v * c2 + s0v * s2v;
    R[1][0] = s0v * c1;
    R[1][1] = s0v * s1v * s2v + c0 * c2;
    R[1][2] = s0v * s1v * c2 - c0 * s2v;
    R[2][0] = -s1v;
    R[2][1] = c1 * s2v;
    R[2][2] = c1 * c2;
    const float SZv[3] = {256.f, 256.f, 16.f};
    const float cen[3] = {128.f, 128.f, 8.f};
    const float tr[3] = {t0, t1, t2};
    float* rt = RT + (b * 4 + t) * 12;
#pragma unroll
    for (int kq = 0; kq < 3; ++kq)
#pragma unroll
      for (int s = 0; s < 3; ++s) rt[kq * 3 + s] = R[kq][s];
#pragma unroll
    for (int s = 0; s < 3; ++s)
      rt[9 + s] = tr[s] * SZv[s] + cen[s] - (128.f * R[0][s] + 128.f * R[1][s] + 8.f * R[2][s]);
  }
}

// ====== flow + grid_out + trilinear grid-sample -> X_t ======
// R13 structure (float2 row-pair loads, 16 VMEM loads/thread): per-VMEM-
// instruction cost is the proven limiter; this is its instruction-count floor.
__global__ __launch_bounds__(256) void k_flow(const float* __restrict__ x,
                                              const float* __restrict__ RT,
                                              float* __restrict__ out) {
  const int raw = blockIdx.x;
  const int bid = (raw & 7) * 4096 + (raw >> 3);   // XCD-contiguous chunk
  const int tid = threadIdx.x;
  const int b = bid >> 12;
  const int l = ((bid & 4095) << 8) | tid;
  const int i = l >> 12, j = (l >> 4) & 255, k = l & 15;
  const float fi = (float)i, fj = (float)j, fk = (float)k;
  const float* __restrict__ rt = RT + b * 48;

  const float txs[4] = {64.f, 64.f, 192.f, 192.f};
  const float tys[4] = {64.f, 192.f, 64.f, 192.f};
  float e[4], es = 0.f;
#pragma unroll
  for (int t = 0; t < 4; ++t) {
    float dx = fi - txs[t], dy = fj - tys[t], dz = fk - 8.f;
    float d = __builtin_amdgcn_sqrtf(fmaf(dx, dx, fmaf(dy, dy, dz * dz)));
    e[t] = __expf(-0.1f * d);
    es += e[t];
  }
  float inv = __builtin_amdgcn_rcpf(es);
  float f0 = 0.f, f1 = 0.f, f2 = 0.f;
#pragma unroll
  for (int t = 0; t < 4; ++t) {
    float wt = e[t] * inv;
    const float* r = rt + t * 12;
    f0 += wt * (fi * r[0] + fj * r[3] + fk * r[6] + r[9]);
    f1 += wt * (fi * r[1] + fj * r[4] + fk * r[7] + r[10]);
    f2 += wt * (fi * r[2] + fj * r[5] + fk * r[8] + r[11]);
  }
  float nf0 = f0 * (1.f / 128.f) - 1.f;
  float nf1 = f1 * (1.f / 128.f) - 1.f;
  float nf2 = f2 * 0.125f - 1.f;

  int gbase = OUT_GRID + ((b << 20) + l) * 3;
  __builtin_nontemporal_store(nf2, &out[gbase]);
  __builtin_nontemporal_store(nf1, &out[gbase + 1]);
  __builtin_nontemporal_store(nf0, &out[gbase + 2]);

  float ix = ((nf2 + 1.f) * 16.f - 1.f) * 0.5f;
  float iy = ((nf1 + 1.f) * 256.f - 1.f) * 0.5f;
  float iz = ((nf0 + 1.f) * 256.f - 1.f) * 0.5f;
  float xf = floorf(ix), yf = floorf(iy), zf = floorf(iz);
  float fx = ix - xf, fy = iy - yf, fz = iz - zf;
  int x0 = (int)xf, y0 = (int)yf, z0 = (int)zf;
  int x1 = x0 + 1, y1 = y0 + 1, z1 = z0 + 1;
  bool vx0 = ((unsigned)x0 < 16u), vx1 = ((unsigned)x1 < 16u);
  bool vy0 = ((unsigned)y0 < 256u), vy1 = ((unsigned)y1 < 256u);
  bool vz0 = ((unsigned)z0 < 256u), vz1 = ((unsigned)z1 < 256u);
  int cx0 = min(max(x0, 0), 15), cx1 = min(max(x1, 0), 15);
  int cy0 = min(max(y0, 0), 255), cy1 = min(max(y1, 0), 255);
  int cz0 = min(max(z0, 0), 255), cz1 = min(max(z1, 0), 255);
  float wx0 = 1.f - fx, wx1 = fx, wy0 = 1.f - fy, wy1 = fy, wz0 = 1.f - fz, wz1 = fz;

  const float wxa = vx0 ? wx0 : 0.f;
  const float wxb = vx1 ? wx1 : 0.f;
  const int base_x = min(cx0, 14);
  const int i0 = cx0 - base_x;
  const int i1 = cx1 - base_x;
  const float ca = (i0 ? 0.f : wxa) + (i1 ? 0.f : wxb);
  const float cb = (i0 ? wxa : 0.f) + (i1 ? wxb : 0.f);

  float W4[4];
  W4[0] = wz0 * wy0 * ((vz0 && vy0) ? 1.f : 0.f);
  W4[1] = wz0 * wy1 * ((vz0 && vy1) ? 1.f : 0.f);
  W4[2] = wz1 * wy0 * ((vz1 && vy0) ? 1.f : 0.f);
  W4[3] = wz1 * wy1 * ((vz1 && vy1) ? 1.f : 0.f);

  int ro[4];
  ro[0] = (cz0 << 12) + (cy0 << 4) + base_x;
  ro[1] = (cz0 << 12) + (cy1 << 4) + base_x;
  ro[2] = (cz1 << 12) + (cy0 << 4) + base_x;
  ro[3] = (cz1 << 12) + (cy1 << 4) + base_x;

  const float* __restrict__ xb0 = x + ((size_t)(b * 4) << 20);

  {
    float2 fa[4], fb[4];
#pragma unroll
    for (int q = 0; q < 4; ++q) __builtin_memcpy(&fa[q], xb0 + ro[q], 8);
#pragma unroll
    for (int q = 0; q < 4; ++q) __builtin_memcpy(&fb[q], xb0 + (1 << 20) + ro[q], 8);
    float s0 = 0.f, s1 = 0.f;
#pragma unroll
    for (int q = 0; q < 4; ++q) {
      s0 = fmaf(W4[q], fmaf(cb, fa[q].y, ca * fa[q].x), s0);
      s1 = fmaf(W4[q], fmaf(cb, fb[q].y, ca * fb[q].x), s1);
    }
    __builtin_nontemporal_store(s0, &out[OUT_XT + ((b * 4 + 0) << 20) + l]);
    __builtin_nontemporal_store(s1, &out[OUT_XT + ((b * 4 + 1) << 20) + l]);
  }
  {
    float2 fa[4], fb[4];
#pragma unroll
    for (int q = 0; q < 4; ++q) __builtin_memcpy(&fa[q], xb0 + (2 << 20) + ro[q], 8);
#pragma unroll
    for (int q = 0; q < 4; ++q) __builtin_memcpy(&fb[q], xb0 + (3 << 20) + ro[q], 8);
    float s0 = 0.f, s1 = 0.f;
#pragma unroll
    for (int q = 0; q < 4; ++q) {
      s0 = fmaf(W4[q], fmaf(cb, fa[q].y, ca * fa[q].x), s0);
      s1 = fmaf(W4[q], fmaf(cb, fb[q].y, ca * fb[q].x), s1);
    }
    __builtin_nontemporal_store(s0, &out[OUT_XT + ((b * 4 + 2) << 20) + l]);
    __builtin_nontemporal_store(s1, &out[OUT_XT + ((b * 4 + 3) << 20) + l]);
  }
}

// ====== moved + reg ======
__global__ __launch_bounds__(256) void k_tail(const float* __restrict__ P,
                                              const float* __restrict__ centers,
                                              const int* __restrict__ times,
                                              float* __restrict__ out) {
  const int b = blockIdx.x, tid = threadIdx.x;
  __shared__ float sred[256];
  float nrm = 0.f;
  if (tid < 200) {
    int tb = times[b];
    float p0 = P[tid * 96 + tb];
    float p1 = P[tid * 96 + 32 + tb];
    float p2 = P[tid * 96 + 64 + tb];
    int i0 = (int)rintf(p0), i1 = (int)rintf(p1), i2 = (int)rintf(p2);
    int lp = (i0 << 12) + (i1 << 4) + i2;
    int gb = OUT_GRID + ((b << 20) + lp) * 3;
    float a0 = out[gb + 2];
    float a1 = out[gb + 1];
    float a2 = out[gb + 0];
    float m0 = 2.f * p0 - (0.5f + 0.5f * a0) * 255.f;
    float m1 = 2.f * p1 - (0.5f + 0.5f * a1) * 255.f;
    float m2 = 2.f * p2 - (0.5f + 0.5f * a2) * 15.f;
    int mo = OUT_MOVED + (b * 200 + tid) * 3;
    out[mo] = m0;
    out[mo + 1] = m1;
    out[mo + 2] = m2;
    float d0 = m0 - centers[tid * 3];
    float d1 = m1 - centers[tid * 3 + 1];
    float d2 = m2 - centers[tid * 3 + 2];
    nrm = sqrtf(d0 * d0 + d1 * d1 + d2 * d2);
  }
  sred[tid] = nrm;
  __syncthreads();
  for (int s = 128; s > 0; s >>= 1) {
    if (tid < s) sred[tid] += sred[tid + s];
    __syncthreads();
  }
  if (tid == 0) out[OUT_REG + b] = sred[0] * 0.005f;
}

extern "C" void kernel_launch(void* const* d_in, const int* in_sizes, int n_in,
                              void* d_out, int out_size, void* d_ws, size_t ws_size,
                              hipStream_t stream) {
  const float* x = (const float*)d_in[0];
  const int* times = (const int*)d_in[1];
  const float* w1 = (const float*)d_in[2];
  const float* b1 = (const float*)d_in[3];
  const float* w2 = (const float*)d_in[4];
  const float* b2 = (const float*)d_in[5];
  const float* fw1 = (const float*)d_in[6];
  const float* fb1 = (const float*)d_in[7];
  const float* fw2 = (const float*)d_in[8];
  const float* fb2 = (const float*)d_in[9];
  const float* P = (const float*)d_in[10];
  const float* centers = (const float*)d_in[11];
  float* out = (float*)d_out;

  float* wt1 = (float*)d_ws;          // 1568 floats
  float* wt2 = wt1 + 1568;            // 2000 floats

  float* buf1 = out + WS_BUF1;
  float* buf2 = out + WS_BUF2;
  float* partial = out + WS_PART;
  float* red = out + WS_RED;
  float* RT = out + WS_RT;

  k_prep<<<1, 256, 0, stream>>>(w1, w2, wt1, wt2);
  for (int zb = 0; zb < 8; zb += 4)
    k_conv1<<<dim3(16, 32, 4), 256, 0, stream>>>(x, wt1, b1, buf1, zb);
  k_conv2<<<dim3(8, 15, 8), 256, 0, stream>>>(buf1, wt2, b2, buf2);
  k_fc1<<<2000, 256, 0, stream>>>(buf2, fw1, partial);
  k_red<<<80, 256, 0, stream>>>(partial, red);
  k_head<<<1, 256, 0, stream>>>(red, fb1, fw2, fb2, RT);
  k_flow<<<32768, 256, 0, stream>>>(x, RT, out);
  k_tail<<<8, 256, 0, stream>>>(P, centers, times, out);
}

// Round 15
// 505.302 us; speedup vs baseline: 1.2243x; 1.0087x over previous
//
#include <hip/hip_runtime.h>
#include <math.h>

// ---- problem constants ----
#define OUT_XT     0
#define OUT_GRID   33554432
#define OUT_REG    58720256
#define OUT_MOVED  58720264
#define FC1_K      576000

// scratch inside d_out (regions consumed before being overwritten):
#define WS_BUF1    0          // (8,8,125,125,16) -- inside X_t region
#define WS_BUF2    16000000   // (8,10,60,60,16)
#define WS_PART    20608000   // 2000 x 256
#define WS_RED     21120000   // 80 x 256
#define WS_RT      58720256   // 8x4x12 -- reg+moved region, overwritten by k_tail

// ======== prep: transpose weights into [ic][dd][oc] for contiguous uniform (s_load) reads ========
__global__ __launch_bounds__(256) void k_prep(const float* __restrict__ w1,
                                              const float* __restrict__ w2,
                                              float* __restrict__ wt1,
                                              float* __restrict__ wt2) {
  const int tid = threadIdx.x;
  for (int t = tid; t < 1568; t += 256) {
    int oc = t & 7, idx = t >> 3;
    int ic = idx / 49, dd = idx % 49;
    wt1[t] = w1[(oc * 4 + ic) * 49 + dd];
  }
  for (int t = tid; t < 2000; t += 256) {
    int oc = t % 10, idx = t / 10;
    int ic = idx / 25, dd = idx % 25;
    wt2[t] = w2[(oc * 8 + ic) * 25 + dd];
  }
}

// ================= conv1 (7x7x1, 4->8) + pool(2,2,1) + relu =================
// R15: wide tile (R14) + SINGLE LDS buffer. 20.6 KB -> ~7 blocks/CU (R14's
// 41 KB dbuf capped occupancy at 37% and ate the wide-tile gain). T14 staging
// kept: next-ic global->reg loads issue before compute; write needs
// barrier-before + barrier-after, covered by the restored TLP.
#define C1_RS 22
#define C1_PS 322
__global__ __launch_bounds__(256) void k_conv1(const float* __restrict__ x,
                                               const float* __restrict__ wt1,
                                               const float* __restrict__ b1,
                                               float* __restrict__ buf1) {
  __shared__ float sIn[16 * C1_PS];
  const int tid = threadIdx.x;
  const int tx = blockIdx.x, ty = blockIdx.y, b = blockIdx.z;

  const int k = tid & 15;
  const int pix = tid >> 4;
  const int pyl = pix >> 2, pxl = pix & 3;
  const int row0 = ty * 8, col0 = tx * 16;

  // staging geometry: 14x22 positions x 4 float4 = 1232 loads, 5 slots
  int sq[5], srow[5], scol[5], sbase[5];
  bool sval[5];
#pragma unroll
  for (int it = 0; it < 5; ++it) {
    int t = tid + it * 256;
    int q = t & 3, pos = t >> 2;
    int coli = pos % 22, rowi = pos / 22;
    sq[it] = q;
    srow[it] = row0 + rowi;
    scol[it] = col0 + coli;
    sbase[it] = rowi * C1_RS + coli;
    sval[it] = (t < 1232) && (srow[it] < 256) && (scol[it] < 256);
  }

  const float4* __restrict__ x4 = reinterpret_cast<const float4*>(x);
  float4 st[5];

#define C1_LOAD(ICV) do {                                                    \
  _Pragma("unroll")                                                          \
  for (int it = 0; it < 5; ++it) {                                           \
    float4 v = make_float4(0.f, 0.f, 0.f, 0.f);                              \
    if (sval[it])                                                            \
      v = x4[(((b * 4 + (ICV)) * 256 + srow[it]) * 256 + scol[it]) * 4 + sq[it]]; \
    st[it] = v;                                                              \
  } } while (0)

#define C1_WRITE() do {                                                      \
  _Pragma("unroll")                                                          \
  for (int it = 0; it < 5; ++it) {                                           \
    if (it < 4 || tid < 208) {                                               \
      float* sp = &sIn[(4 * sq[it]) * C1_PS + sbase[it]];                    \
      sp[0 * C1_PS] = st[it].x;                                              \
      sp[1 * C1_PS] = st[it].y;                                              \
      sp[2 * C1_PS] = st[it].z;                                              \
      sp[3 * C1_PS] = st[it].w;                                              \
    }                                                                        \
  } } while (0)

  float acc[2][4][8];
#pragma unroll
  for (int a = 0; a < 2; ++a)
#pragma unroll
    for (int c = 0; c < 4; ++c)
#pragma unroll
      for (int oc = 0; oc < 8; ++oc) acc[a][c][oc] = 0.f;

  C1_LOAD(0);
  C1_WRITE();
  __syncthreads();

#pragma unroll 1
  for (int ic = 0; ic < 4; ++ic) {
    if (ic < 3) C1_LOAD(ic + 1);        // T14: HBM latency hides under compute
#pragma unroll 1
    for (int dy = 0; dy < 7; ++dy) {
      float v[2][10];
#pragma unroll
      for (int a = 0; a < 2; ++a) {
        const int base = k * C1_PS + (2 * pyl + a + dy) * C1_RS + 4 * pxl;
#pragma unroll
        for (int j = 0; j < 5; ++j) {
          float2 f = *reinterpret_cast<const float2*>(&sIn[base + 2 * j]);
          v[a][2 * j] = f.x;
          v[a][2 * j + 1] = f.y;
        }
      }
      const float* __restrict__ wd = wt1 + ic * 392 + dy * 56;   // uniform -> s_load
#pragma unroll
      for (int dx = 0; dx < 7; ++dx) {
#pragma unroll
        for (int a = 0; a < 2; ++a)
#pragma unroll
          for (int c = 0; c < 4; ++c) {
            const float val = v[a][c + dx];
#pragma unroll
            for (int oc = 0; oc < 8; ++oc)
              acc[a][c][oc] = fmaf(val, wd[dx * 8 + oc], acc[a][c][oc]);
          }
      }
    }
    if (ic < 3) {
      __syncthreads();                  // all readers done with sIn
      C1_WRITE();
      __syncthreads();                  // next tile visible
    }
  }
#undef C1_LOAD
#undef C1_WRITE

  const int py = ty * 4 + pyl;
  if (py < 125) {
#pragma unroll
    for (int cc = 0; cc < 2; ++cc) {
      const int px = tx * 8 + 2 * pxl + cc;
      if (px < 125) {
#pragma unroll
        for (int oc = 0; oc < 8; ++oc) {
          float m = fmaxf(fmaxf(acc[0][2 * cc][oc], acc[0][2 * cc + 1][oc]),
                          fmaxf(acc[1][2 * cc][oc], acc[1][2 * cc + 1][oc])) + b1[oc];
          buf1[(((b * 8 + oc) * 125 + py) * 125 + px) * 16 + k] = fmaxf(m, 0.f);
        }
      }
    }
  }
}

// ================= conv2 (5x5x1, 8->10) + pool + relu =================
// Wide tile + single buffer (16.5 KB -> 8 blocks/CU).
#define C2_RS 20
#define C2_PS 258
__global__ __launch_bounds__(256) void k_conv2(const float* __restrict__ in,
                                               const float* __restrict__ wt2,
                                               const float* __restrict__ b2,
                                               float* __restrict__ buf2) {
  __shared__ float sIn[16 * C2_PS];
  const int tid = threadIdx.x;
  const int tx = blockIdx.x, ty = blockIdx.y, b = blockIdx.z;

  const int k = tid & 15;
  const int pix = tid >> 4;
  const int pyl = pix >> 2, pxl = pix & 3;
  const int row0 = ty * 8, col0 = tx * 16;

  int sq[4], srow[4], scol[4], sbase[4];
  bool sval[4];
#pragma unroll
  for (int it = 0; it < 4; ++it) {
    int t = tid + it * 256;
    int q = t & 3, pos = t >> 2;
    int coli = pos % 20, rowi = pos / 20;
    sq[it] = q;
    srow[it] = row0 + rowi;                 // <= 123, always in-bounds
    scol[it] = col0 + coli;
    sbase[it] = rowi * C2_RS + coli;
    sval[it] = (t < 960) && (scol[it] < 125);
  }

  const float4* __restrict__ in4 = reinterpret_cast<const float4*>(in);
  float4 st[4];

#define C2_LOAD(ICV) do {                                                    \
  _Pragma("unroll")                                                          \
  for (int it = 0; it < 4; ++it) {                                           \
    float4 v = make_float4(0.f, 0.f, 0.f, 0.f);                              \
    if (sval[it])                                                            \
      v = in4[(((b * 8 + (ICV)) * 125 + srow[it]) * 125 + scol[it]) * 4 + sq[it]]; \
    st[it] = v;                                                              \
  } } while (0)

#define C2_WRITE() do {                                                      \
  _Pragma("unroll")                                                          \
  for (int it = 0; it < 4; ++it) {                                           \
    if (it < 3 || tid < 192) {                                               \
      float* sp = &sIn[(4 * sq[it]) * C2_PS + sbase[it]];                    \
      sp[0 * C2_PS] = st[it].x;                                              \
      sp[1 * C2_PS] = st[it].y;                                              \
      sp[2 * C2_PS] = st[it].z;                                              \
      sp[3 * C2_PS] = st[it].w;                                              \
    }                                                                        \
  } } while (0)

  float acc[2][4][10];
#pragma unroll
  for (int a = 0; a < 2; ++a)
#pragma unroll
    for (int c = 0; c < 4; ++c)
#pragma unroll
      for (int oc = 0; oc < 10; ++oc) acc[a][c][oc] = 0.f;

  C2_LOAD(0);
  C2_WRITE();
  __syncthreads();

#pragma unroll 1
  for (int ic = 0; ic < 8; ++ic) {
    if (ic < 7) C2_LOAD(ic + 1);
#pragma unroll 1
    for (int dy = 0; dy < 5; ++dy) {
      float v[2][8];
#pragma unroll
      for (int a = 0; a < 2; ++a) {
        const int base = k * C2_PS + (2 * pyl + a + dy) * C2_RS + 4 * pxl;
#pragma unroll
        for (int j = 0; j < 4; ++j) {
          float2 f = *reinterpret_cast<const float2*>(&sIn[base + 2 * j]);
          v[a][2 * j] = f.x;
          v[a][2 * j + 1] = f.y;
        }
      }
      const float* __restrict__ wd = wt2 + ic * 250 + dy * 50;   // uniform -> s_load
#pragma unroll
      for (int dx = 0; dx < 5; ++dx) {
#pragma unroll
        for (int a = 0; a < 2; ++a)
#pragma unroll
          for (int c = 0; c < 4; ++c) {
            const float val = v[a][c + dx];
#pragma unroll
            for (int oc = 0; oc < 10; ++oc)
              acc[a][c][oc] = fmaf(val, wd[dx * 10 + oc], acc[a][c][oc]);
          }
      }
    }
    if (ic < 7) {
      __syncthreads();
      C2_WRITE();
      __syncthreads();
    }
  }
#undef C2_LOAD
#undef C2_WRITE

  const int py = ty * 4 + pyl;        // <= 59, always valid
#pragma unroll
  for (int cc = 0; cc < 2; ++cc) {
    const int px = tx * 8 + 2 * pxl + cc;
    if (px < 60) {
#pragma unroll
      for (int oc = 0; oc < 10; ++oc) {
        float m = fmaxf(fmaxf(acc[0][2 * cc][oc], acc[0][2 * cc + 1][oc]),
                        fmaxf(acc[1][2 * cc][oc], acc[1][2 * cc + 1][oc])) + b2[oc];
        buf2[(((b * 10 + oc) * 60 + py) * 60 + px) * 16 + k] = fmaxf(m, 0.f);
      }
    }
  }
}

// ================= fc1 split-K pass 1: partial[2000][256], float4 loads =================
__global__ __launch_bounds__(256) void k_fc1(const float* __restrict__ z,
                                             const float* __restrict__ w,
                                             float* __restrict__ partial) {
  const int bid = blockIdx.x, tid = threadIdx.x;
  const int b = tid >> 5, o = tid & 31;
  const int k0 = bid * 288;                 // 2000 * 288 == 576000
  const float4* __restrict__ zp = reinterpret_cast<const float4*>(z + b * FC1_K + k0);
  const float4* __restrict__ wp = reinterpret_cast<const float4*>(w + o * FC1_K + k0);
  float a0 = 0.f, a1 = 0.f, a2 = 0.f, a3 = 0.f;
  float a4 = 0.f, a5 = 0.f, a6 = 0.f, a7 = 0.f;
#pragma unroll 2
  for (int i = 0; i < 72; i += 2) {
    float4 z0 = zp[i], w0 = wp[i];
    float4 z1 = zp[i + 1], w1 = wp[i + 1];
    a0 = fmaf(z0.x, w0.x, a0);
    a1 = fmaf(z0.y, w0.y, a1);
    a2 = fmaf(z0.z, w0.z, a2);
    a3 = fmaf(z0.w, w0.w, a3);
    a4 = fmaf(z1.x, w1.x, a4);
    a5 = fmaf(z1.y, w1.y, a5);
    a6 = fmaf(z1.z, w1.z, a6);
    a7 = fmaf(z1.w, w1.w, a7);
  }
  partial[bid * 256 + tid] = ((a0 + a1) + (a2 + a3)) + ((a4 + a5) + (a6 + a7));
}

// ======== red: partial[2000][256] -> red[80][256] ========
__global__ __launch_bounds__(256) void k_red(const float* __restrict__ partial,
                                             float* __restrict__ red) {
  const int bl = blockIdx.x, tid = threadIdx.x;
  const float* __restrict__ p = partial + bl * 25 * 256 + tid;
  float s0 = 0.f, s1 = 0.f, s2 = 0.f, s3 = 0.f, s4 = 0.f;
#pragma unroll
  for (int i = 0; i < 25; i += 5) {
    s0 += p[i * 256];
    s1 += p[(i + 1) * 256];
    s2 += p[(i + 2) * 256];
    s3 += p[(i + 3) * 256];
    s4 += p[(i + 4) * 256];
  }
  red[bl * 256 + tid] = ((s0 + s1) + (s2 + s3)) + s4;
}

// ======== head: reduce red[80][256] -> fc1 relu -> fc2 tanh -> R, Tv ========
__global__ __launch_bounds__(256) void k_head(const float* __restrict__ red,
                                              const float* __restrict__ fc1_b,
                                              const float* __restrict__ fc2_w,
                                              const float* __restrict__ fc2_b,
                                              float* __restrict__ RT) {
  __shared__ float sH[256];
  __shared__ float sTh[8][24];
  const int tid = threadIdx.x;
  float s0 = 0.f, s1 = 0.f, s2 = 0.f, s3 = 0.f;
#pragma unroll
  for (int c = 0; c < 80; c += 4) {
    s0 += red[c * 256 + tid];
    s1 += red[(c + 1) * 256 + tid];
    s2 += red[(c + 2) * 256 + tid];
    s3 += red[(c + 3) * 256 + tid];
  }
  const int o = tid & 31;
  sH[tid] = fmaxf(((s0 + s1) + (s2 + s3)) + fc1_b[o], 0.f);
  __syncthreads();
  if (tid < 192) {
    int b = tid / 24, o2 = tid % 24;
    float a = fc2_b[o2];
#pragma unroll
    for (int i = 0; i < 32; ++i) a = fmaf(sH[b * 32 + i], fc2_w[o2 * 32 + i], a);
    sTh[b][o2] = tanhf(a);
  }
  __syncthreads();
  if (tid < 32) {
    const int b = tid >> 2, t = tid & 3;
    const float PI = 3.14159265358979323846f;
    float a0 = PI * sTh[b][t * 6 + 0];
    float a1 = PI * sTh[b][t * 6 + 1];
    float a2 = PI * sTh[b][t * 6 + 2];
    float t0 = sTh[b][t * 6 + 3], t1 = sTh[b][t * 6 + 4], t2 = sTh[b][t * 6 + 5];
    float c0 = cosf(a0), s0v = sinf(a0);
    float c1 = cosf(a1), s1v = sinf(a1);
    float c2 = cosf(a2), s2v = sinf(a2);
    float R[3][3];
    R[0][0] = c0 * c1;
    R[0][1] = c0 * s1v * s2v - s0v * c2;
    R[0][2] = c0 * s1v * c2 + s0v * s2v;
    R[1][0] = s0v * c1;
    R[1][1] = s0v * s1v * s2v + c0 * c2;
    R[1][2] = s0v * s1v * c2 - c0 * s2v;
    R[2][0] = -s1v;
    R[2][1] = c1 * s2v;
    R[2][2] = c1 * c2;
    const float SZv[3] = {256.f, 256.f, 16.f};
    const float cen[3] = {128.f, 128.f, 8.f};
    const float tr[3] = {t0, t1, t2};
    float* rt = RT + (b * 4 + t) * 12;
#pragma unroll
    for (int kq = 0; kq < 3; ++kq)
#pragma unroll
      for (int s = 0; s < 3; ++s) rt[kq * 3 + s] = R[kq][s];
#pragma unroll
    for (int s = 0; s < 3; ++s)
      rt[9 + s] = tr[s] * SZv[s] + cen[s] - (128.f * R[0][s] + 128.f * R[1][s] + 8.f * R[2][s]);
  }
}

// ====== flow + grid_out + trilinear grid-sample -> X_t ======
// R13 structure (float2 row-pair loads, 16 gather + 7 store VMEM instr/thread):
// per-VMEM-instruction cost is the proven limiter; this is its instr-count floor.
__global__ __launch_bounds__(256) void k_flow(const float* __restrict__ x,
                                              const float* __restrict__ RT,
                                              float* __restrict__ out) {
  const int raw = blockIdx.x;
  const int bid = (raw & 7) * 4096 + (raw >> 3);   // XCD-contiguous chunk
  const int tid = threadIdx.x;
  const int b = bid >> 12;
  const int l = ((bid & 4095) << 8) | tid;
  const int i = l >> 12, j = (l >> 4) & 255, k = l & 15;
  const float fi = (float)i, fj = (float)j, fk = (float)k;
  const float* __restrict__ rt = RT + b * 48;

  const float txs[4] = {64.f, 64.f, 192.f, 192.f};
  const float tys[4] = {64.f, 192.f, 64.f, 192.f};
  float e[4], es = 0.f;
#pragma unroll
  for (int t = 0; t < 4; ++t) {
    float dx = fi - txs[t], dy = fj - tys[t], dz = fk - 8.f;
    float d = __builtin_amdgcn_sqrtf(fmaf(dx, dx, fmaf(dy, dy, dz * dz)));
    e[t] = __expf(-0.1f * d);
    es += e[t];
  }
  float inv = __builtin_amdgcn_rcpf(es);
  float f0 = 0.f, f1 = 0.f, f2 = 0.f;
#pragma unroll
  for (int t = 0; t < 4; ++t) {
    float wt = e[t] * inv;
    const float* r = rt + t * 12;
    f0 += wt * (fi * r[0] + fj * r[3] + fk * r[6] + r[9]);
    f1 += wt * (fi * r[1] + fj * r[4] + fk * r[7] + r[10]);
    f2 += wt * (fi * r[2] + fj * r[5] + fk * r[8] + r[11]);
  }
  float nf0 = f0 * (1.f / 128.f) - 1.f;
  float nf1 = f1 * (1.f / 128.f) - 1.f;
  float nf2 = f2 * 0.125f - 1.f;

  int gbase = OUT_GRID + ((b << 20) + l) * 3;
  __builtin_nontemporal_store(nf2, &out[gbase]);
  __builtin_nontemporal_store(nf1, &out[gbase + 1]);
  __builtin_nontemporal_store(nf0, &out[gbase + 2]);

  float ix = ((nf2 + 1.f) * 16.f - 1.f) * 0.5f;
  float iy = ((nf1 + 1.f) * 256.f - 1.f) * 0.5f;
  float iz = ((nf0 + 1.f) * 256.f - 1.f) * 0.5f;
  float xf = floorf(ix), yf = floorf(iy), zf = floorf(iz);
  float fx = ix - xf, fy = iy - yf, fz = iz - zf;
  int x0 = (int)xf, y0 = (int)yf, z0 = (int)zf;
  int x1 = x0 + 1, y1 = y0 + 1, z1 = z0 + 1;
  bool vx0 = ((unsigned)x0 < 16u), vx1 = ((unsigned)x1 < 16u);
  bool vy0 = ((unsigned)y0 < 256u), vy1 = ((unsigned)y1 < 256u);
  bool vz0 = ((unsigned)z0 < 256u), vz1 = ((unsigned)z1 < 256u);
  int cx0 = min(max(x0, 0), 15), cx1 = min(max(x1, 0), 15);
  int cy0 = min(max(y0, 0), 255), cy1 = min(max(y1, 0), 255);
  int cz0 = min(max(z0, 0), 255), cz1 = min(max(z1, 0), 255);
  float wx0 = 1.f - fx, wx1 = fx, wy0 = 1.f - fy, wy1 = fy, wz0 = 1.f - fz, wz1 = fz;

  const float wxa = vx0 ? wx0 : 0.f;
  const float wxb = vx1 ? wx1 : 0.f;
  const int base_x = min(cx0, 14);
  const int i0 = cx0 - base_x;
  const int i1 = cx1 - base_x;
  const float ca = (i0 ? 0.f : wxa) + (i1 ? 0.f : wxb);
  const float cb = (i0 ? wxa : 0.f) + (i1 ? wxb : 0.f);

  float W4[4];
  W4[0] = wz0 * wy0 * ((vz0 && vy0) ? 1.f : 0.f);
  W4[1] = wz0 * wy1 * ((vz0 && vy1) ? 1.f : 0.f);
  W4[2] = wz1 * wy0 * ((vz1 && vy0) ? 1.f : 0.f);
  W4[3] = wz1 * wy1 * ((vz1 && vy1) ? 1.f : 0.f);

  int ro[4];
  ro[0] = (cz0 << 12) + (cy0 << 4) + base_x;
  ro[1] = (cz0 << 12) + (cy1 << 4) + base_x;
  ro[2] = (cz1 << 12) + (cy0 << 4) + base_x;
  ro[3] = (cz1 << 12) + (cy1 << 4) + base_x;

  const float* __restrict__ xb0 = x + ((size_t)(b * 4) << 20);

  {
    float2 fa[4], fb[4];
#pragma unroll
    for (int q = 0; q < 4; ++q) __builtin_memcpy(&fa[q], xb0 + ro[q], 8);
#pragma unroll
    for (int q = 0; q < 4; ++q) __builtin_memcpy(&fb[q], xb0 + (1 << 20) + ro[q], 8);
    float s0 = 0.f, s1 = 0.f;
#pragma unroll
    for (int q = 0; q < 4; ++q) {
      s0 = fmaf(W4[q], fmaf(cb, fa[q].y, ca * fa[q].x), s0);
      s1 = fmaf(W4[q], fmaf(cb, fb[q].y, ca * fb[q].x), s1);
    }
    __builtin_nontemporal_store(s0, &out[OUT_XT + ((b * 4 + 0) << 20) + l]);
    __builtin_nontemporal_store(s1, &out[OUT_XT + ((b * 4 + 1) << 20) + l]);
  }
  {
    float2 fa[4], fb[4];
#pragma unroll
    for (int q = 0; q < 4; ++q) __builtin_memcpy(&fa[q], xb0 + (2 << 20) + ro[q], 8);
#pragma unroll
    for (int q = 0; q < 4; ++q) __builtin_memcpy(&fb[q], xb0 + (3 << 20) + ro[q], 8);
    float s0 = 0.f, s1 = 0.f;
#pragma unroll
    for (int q = 0; q < 4; ++q) {
      s0 = fmaf(W4[q], fmaf(cb, fa[q].y, ca * fa[q].x), s0);
      s1 = fmaf(W4[q], fmaf(cb, fb[q].y, ca * fb[q].x), s1);
    }
    __builtin_nontemporal_store(s0, &out[OUT_XT + ((b * 4 + 2) << 20) + l]);
    __builtin_nontemporal_store(s1, &out[OUT_XT + ((b * 4 + 3) << 20) + l]);
  }
}

// ====== moved + reg ======
__global__ __launch_bounds__(256) void k_tail(const float* __restrict__ P,
                                              const float* __restrict__ centers,
                                              const int* __restrict__ times,
                                              float* __restrict__ out) {
  const int b = blockIdx.x, tid = threadIdx.x;
  __shared__ float sred[256];
  float nrm = 0.f;
  if (tid < 200) {
    int tb = times[b];
    float p0 = P[tid * 96 + tb];
    float p1 = P[tid * 96 + 32 + tb];
    float p2 = P[tid * 96 + 64 + tb];
    int i0 = (int)rintf(p0), i1 = (int)rintf(p1), i2 = (int)rintf(p2);
    int lp = (i0 << 12) + (i1 << 4) + i2;
    int gb = OUT_GRID + ((b << 20) + lp) * 3;
    float a0 = out[gb + 2];
    float a1 = out[gb + 1];
    float a2 = out[gb + 0];
    float m0 = 2.f * p0 - (0.5f + 0.5f * a0) * 255.f;
    float m1 = 2.f * p1 - (0.5f + 0.5f * a1) * 255.f;
    float m2 = 2.f * p2 - (0.5f + 0.5f * a2) * 15.f;
    int mo = OUT_MOVED + (b * 200 + tid) * 3;
    out[mo] = m0;
    out[mo + 1] = m1;
    out[mo + 2] = m2;
    float d0 = m0 - centers[tid * 3];
    float d1 = m1 - centers[tid * 3 + 1];
    float d2 = m2 - centers[tid * 3 + 2];
    nrm = sqrtf(d0 * d0 + d1 * d1 + d2 * d2);
  }
  sred[tid] = nrm;
  __syncthreads();
  for (int s = 128; s > 0; s >>= 1) {
    if (tid < s) sred[tid] += sred[tid + s];
    __syncthreads();
  }
  if (tid == 0) out[OUT_REG + b] = sred[0] * 0.005f;
}

extern "C" void kernel_launch(void* const* d_in, const int* in_sizes, int n_in,
                              void* d_out, int out_size, void* d_ws, size_t ws_size,
                              hipStream_t stream) {
  const float* x = (const float*)d_in[0];
  const int* times = (const int*)d_in[1];
  const float* w1 = (const float*)d_in[2];
  const float* b1 = (const float*)d_in[3];
  const float* w2 = (const float*)d_in[4];
  const float* b2 = (const float*)d_in[5];
  const float* fw1 = (const float*)d_in[6];
  const float* fb1 = (const float*)d_in[7];
  const float* fw2 = (const float*)d_in[8];
  const float* fb2 = (const float*)d_in[9];
  const float* P = (const float*)d_in[10];
  const float* centers = (const float*)d_in[11];
  float* out = (float*)d_out;

  float* wt1 = (float*)d_ws;          // 1568 floats
  float* wt2 = wt1 + 1568;            // 2000 floats

  float* buf1 = out + WS_BUF1;
  float* buf2 = out + WS_BUF2;
  float* partial = out + WS_PART;
  float* red = out + WS_RED;
  float* RT = out + WS_RT;

  k_prep<<<1, 256, 0, stream>>>(w1, w2, wt1, wt2);
  k_conv1<<<dim3(16, 32, 8), 256, 0, stream>>>(x, wt1, b1, buf1);
  k_conv2<<<dim3(8, 15, 8), 256, 0, stream>>>(buf1, wt2, b2, buf2);
  k_fc1<<<2000, 256, 0, stream>>>(buf2, fw1, partial);
  k_red<<<80, 256, 0, stream>>>(partial, red);
  k_head<<<1, 256, 0, stream>>>(red, fb1, fw2, fb2, RT);
  k_flow<<<32768, 256, 0, stream>>>(x, RT, out);
  k_tail<<<8, 256, 0, stream>>>(P, centers, times, out);
}

// Round 17
// 454.688 us; speedup vs baseline: 1.3606x; 1.1113x over previous
//
#include <hip/hip_runtime.h>
#include <math.h>

// ---- problem constants ----
#define OUT_XT     0
#define OUT_GRID   33554432
#define OUT_REG    58720256
#define OUT_MOVED  58720264
#define FC1_K      576000

// scratch inside d_out (regions consumed before being overwritten):
#define WS_BUF1    0          // (8,8,125,125,16) -- inside X_t region
#define WS_BUF2    16000000   // (8,10,60,60,16)
#define WS_PART    20608000   // 2250 x 256 = 576000
#define WS_RED     21184000   // 90 x 256
#define WS_RT      58720256   // 8x4x12 -- reg+moved region, overwritten by k_tail

// ======== prep: transpose weights into [ic][dd][oc] for contiguous uniform (s_load) reads ========
__global__ __launch_bounds__(256) void k_prep(const float* __restrict__ w1,
                                              const float* __restrict__ w2,
                                              float* __restrict__ wt1,
                                              float* __restrict__ wt2) {
  const int tid = threadIdx.x;
  for (int t = tid; t < 1568; t += 256) {
    int oc = t & 7, idx = t >> 3;
    int ic = idx / 49, dd = idx % 49;
    wt1[t] = w1[(oc * 4 + ic) * 49 + dd];
  }
  for (int t = tid; t < 2000; t += 256) {
    int oc = t % 10, idx = t / 10;
    int ic = idx / 25, dd = idx % 25;
    wt2[t] = w2[(oc * 8 + ic) * 25 + dd];
  }
}

// ================= conv1 (7x7x1, 4->8) + pool(2,2,1) + relu =================
// R15 structure (proven best): wide tile + single LDS buffer + T14 staging.
#define C1_RS 22
#define C1_PS 322
__global__ __launch_bounds__(256) void k_conv1(const float* __restrict__ x,
                                               const float* __restrict__ wt1,
                                               const float* __restrict__ b1,
                                               float* __restrict__ buf1) {
  __shared__ float sIn[16 * C1_PS];
  const int tid = threadIdx.x;
  const int tx = blockIdx.x, ty = blockIdx.y, b = blockIdx.z;

  const int k = tid & 15;
  const int pix = tid >> 4;
  const int pyl = pix >> 2, pxl = pix & 3;
  const int row0 = ty * 8, col0 = tx * 16;

  int sq[5], srow[5], scol[5], sbase[5];
  bool sval[5];
#pragma unroll
  for (int it = 0; it < 5; ++it) {
    int t = tid + it * 256;
    int q = t & 3, pos = t >> 2;
    int coli = pos % 22, rowi = pos / 22;
    sq[it] = q;
    srow[it] = row0 + rowi;
    scol[it] = col0 + coli;
    sbase[it] = rowi * C1_RS + coli;
    sval[it] = (t < 1232) && (srow[it] < 256) && (scol[it] < 256);
  }

  const float4* __restrict__ x4 = reinterpret_cast<const float4*>(x);
  float4 st[5];

#define C1_LOAD(ICV) do {                                                    \
  _Pragma("unroll")                                                          \
  for (int it = 0; it < 5; ++it) {                                           \
    float4 v = make_float4(0.f, 0.f, 0.f, 0.f);                              \
    if (sval[it])                                                            \
      v = x4[(((b * 4 + (ICV)) * 256 + srow[it]) * 256 + scol[it]) * 4 + sq[it]]; \
    st[it] = v;                                                              \
  } } while (0)

#define C1_WRITE() do {                                                      \
  _Pragma("unroll")                                                          \
  for (int it = 0; it < 5; ++it) {                                           \
    if (it < 4 || tid < 208) {                                               \
      float* sp = &sIn[(4 * sq[it]) * C1_PS + sbase[it]];                    \
      sp[0 * C1_PS] = st[it].x;                                              \
      sp[1 * C1_PS] = st[it].y;                                              \
      sp[2 * C1_PS] = st[it].z;                                              \
      sp[3 * C1_PS] = st[it].w;                                              \
    }                                                                        \
  } } while (0)

  float acc[2][4][8];
#pragma unroll
  for (int a = 0; a < 2; ++a)
#pragma unroll
    for (int c = 0; c < 4; ++c)
#pragma unroll
      for (int oc = 0; oc < 8; ++oc) acc[a][c][oc] = 0.f;

  C1_LOAD(0);
  C1_WRITE();
  __syncthreads();

#pragma unroll 1
  for (int ic = 0; ic < 4; ++ic) {
    if (ic < 3) C1_LOAD(ic + 1);
#pragma unroll 1
    for (int dy = 0; dy < 7; ++dy) {
      float v[2][10];
#pragma unroll
      for (int a = 0; a < 2; ++a) {
        const int base = k * C1_PS + (2 * pyl + a + dy) * C1_RS + 4 * pxl;
#pragma unroll
        for (int j = 0; j < 5; ++j) {
          float2 f = *reinterpret_cast<const float2*>(&sIn[base + 2 * j]);
          v[a][2 * j] = f.x;
          v[a][2 * j + 1] = f.y;
        }
      }
      const float* __restrict__ wd = wt1 + ic * 392 + dy * 56;   // uniform -> s_load
#pragma unroll
      for (int dx = 0; dx < 7; ++dx) {
#pragma unroll
        for (int a = 0; a < 2; ++a)
#pragma unroll
          for (int c = 0; c < 4; ++c) {
            const float val = v[a][c + dx];
#pragma unroll
            for (int oc = 0; oc < 8; ++oc)
              acc[a][c][oc] = fmaf(val, wd[dx * 8 + oc], acc[a][c][oc]);
          }
      }
    }
    if (ic < 3) {
      __syncthreads();
      C1_WRITE();
      __syncthreads();
    }
  }
#undef C1_LOAD
#undef C1_WRITE

  const int py = ty * 4 + pyl;
  if (py < 125) {
#pragma unroll
    for (int cc = 0; cc < 2; ++cc) {
      const int px = tx * 8 + 2 * pxl + cc;
      if (px < 125) {
#pragma unroll
        for (int oc = 0; oc < 8; ++oc) {
          float m = fmaxf(fmaxf(acc[0][2 * cc][oc], acc[0][2 * cc + 1][oc]),
                          fmaxf(acc[1][2 * cc][oc], acc[1][2 * cc + 1][oc])) + b1[oc];
          buf1[(((b * 8 + oc) * 125 + py) * 125 + px) * 16 + k] = fmaxf(m, 0.f);
        }
      }
    }
  }
}

// ================= conv2 (5x5x1, 8->10) + pool + relu =================
#define C2_RS 20
#define C2_PS 258
__global__ __launch_bounds__(256) void k_conv2(const float* __restrict__ in,
                                               const float* __restrict__ wt2,
                                               const float* __restrict__ b2,
                                               float* __restrict__ buf2) {
  __shared__ float sIn[16 * C2_PS];
  const int tid = threadIdx.x;
  const int tx = blockIdx.x, ty = blockIdx.y, b = blockIdx.z;

  const int k = tid & 15;
  const int pix = tid >> 4;
  const int pyl = pix >> 2, pxl = pix & 3;
  const int row0 = ty * 8, col0 = tx * 16;

  int sq[4], srow[4], scol[4], sbase[4];
  bool sval[4];
#pragma unroll
  for (int it = 0; it < 4; ++it) {
    int t = tid + it * 256;
    int q = t & 3, pos = t >> 2;
    int coli = pos % 20, rowi = pos / 20;
    sq[it] = q;
    srow[it] = row0 + rowi;
    scol[it] = col0 + coli;
    sbase[it] = rowi * C2_RS + coli;
    sval[it] = (t < 960) && (scol[it] < 125);
  }

  const float4* __restrict__ in4 = reinterpret_cast<const float4*>(in);
  float4 st[4];

#define C2_LOAD(ICV) do {                                                    \
  _Pragma("unroll")                                                          \
  for (int it = 0; it < 4; ++it) {                                           \
    float4 v = make_float4(0.f, 0.f, 0.f, 0.f);                              \
    if (sval[it])                                                            \
      v = in4[(((b * 8 + (ICV)) * 125 + srow[it]) * 125 + scol[it]) * 4 + sq[it]]; \
    st[it] = v;                                                              \
  } } while (0)

#define C2_WRITE() do {                                                      \
  _Pragma("unroll")                                                          \
  for (int it = 0; it < 4; ++it) {                                           \
    if (it < 3 || tid < 192) {                                               \
      float* sp = &sIn[(4 * sq[it]) * C2_PS + sbase[it]];                    \
      sp[0 * C2_PS] = st[it].x;                                              \
      sp[1 * C2_PS] = st[it].y;                                              \
      sp[2 * C2_PS] = st[it].z;                                              \
      sp[3 * C2_PS] = st[it].w;                                              \
    }                                                                        \
  } } while (0)

  float acc[2][4][10];
#pragma unroll
  for (int a = 0; a < 2; ++a)
#pragma unroll
    for (int c = 0; c < 4; ++c)
#pragma unroll
      for (int oc = 0; oc < 10; ++oc) acc[a][c][oc] = 0.f;

  C2_LOAD(0);
  C2_WRITE();
  __syncthreads();

#pragma unroll 1
  for (int ic = 0; ic < 8; ++ic) {
    if (ic < 7) C2_LOAD(ic + 1);
#pragma unroll 1
    for (int dy = 0; dy < 5; ++dy) {
      float v[2][8];
#pragma unroll
      for (int a = 0; a < 2; ++a) {
        const int base = k * C2_PS + (2 * pyl + a + dy) * C2_RS + 4 * pxl;
#pragma unroll
        for (int j = 0; j < 4; ++j) {
          float2 f = *reinterpret_cast<const float2*>(&sIn[base + 2 * j]);
          v[a][2 * j] = f.x;
          v[a][2 * j + 1] = f.y;
        }
      }
      const float* __restrict__ wd = wt2 + ic * 250 + dy * 50;   // uniform -> s_load
#pragma unroll
      for (int dx = 0; dx < 5; ++dx) {
#pragma unroll
        for (int a = 0; a < 2; ++a)
#pragma unroll
          for (int c = 0; c < 4; ++c) {
            const float val = v[a][c + dx];
#pragma unroll
            for (int oc = 0; oc < 10; ++oc)
              acc[a][c][oc] = fmaf(val, wd[dx * 10 + oc], acc[a][c][oc]);
          }
      }
    }
    if (ic < 7) {
      __syncthreads();
      C2_WRITE();
      __syncthreads();
    }
  }
#undef C2_LOAD
#undef C2_WRITE

  const int py = ty * 4 + pyl;
#pragma unroll
  for (int cc = 0; cc < 2; ++cc) {
    const int px = tx * 8 + 2 * pxl + cc;
    if (px < 60) {
#pragma unroll
      for (int oc = 0; oc < 10; ++oc) {
        float m = fmaxf(fmaxf(acc[0][2 * cc][oc], acc[0][2 * cc + 1][oc]),
                        fmaxf(acc[1][2 * cc][oc], acc[1][2 * cc + 1][oc])) + b2[oc];
        buf2[(((b * 10 + oc) * 60 + py) * 60 + px) * 16 + k] = fmaxf(m, 0.f);
      }
    }
  }
}

// ================= fc1 split-K: coalesced via LDS bounce =================
// R17 fix: z-staging needs 512 work items -> strided loop (R16's `if (tid<512)`
// with 256 threads left sZ rows 4..7 uninitialized -> wrong theta for b>=4).
__global__ __launch_bounds__(256) void k_fc1(const float* __restrict__ z,
                                             const float* __restrict__ w,
                                             float* __restrict__ partial) {
  __shared__ float sW[32 * 260];
  __shared__ float sZ[8 * 256];
  const int bid = blockIdx.x, tid = threadIdx.x;
  const int k0 = bid * 256;

  // stage w: 32 rows x 64 float4
  for (int t = tid; t < 2048; t += 256) {
    int o = t >> 6, kq = t & 63;
    float4 v = *reinterpret_cast<const float4*>(w + o * FC1_K + k0 + 4 * kq);
    *reinterpret_cast<float4*>(&sW[o * 260 + 4 * kq]) = v;
  }
  // stage z: 8 rows x 64 float4 = 512 items (strided loop!)
  for (int t = tid; t < 512; t += 256) {
    int b = t >> 6, kq = t & 63;
    *reinterpret_cast<float4*>(&sZ[b * 256 + 4 * kq]) =
        *reinterpret_cast<const float4*>(z + b * FC1_K + k0 + 4 * kq);
  }
  __syncthreads();

  const int b = tid >> 5, o = tid & 31;
  const float* __restrict__ zp = &sZ[b * 256];
  const float* __restrict__ wp = &sW[o * 260];
  float a0 = 0.f, a1 = 0.f, a2 = 0.f, a3 = 0.f;
  float a4 = 0.f, a5 = 0.f, a6 = 0.f, a7 = 0.f;
#pragma unroll
  for (int kk = 0; kk < 256; kk += 8) {
    float4 z0 = *reinterpret_cast<const float4*>(zp + kk);
    float4 w0 = *reinterpret_cast<const float4*>(wp + kk);
    float4 z1 = *reinterpret_cast<const float4*>(zp + kk + 4);
    float4 w1 = *reinterpret_cast<const float4*>(wp + kk + 4);
    a0 = fmaf(z0.x, w0.x, a0);
    a1 = fmaf(z0.y, w0.y, a1);
    a2 = fmaf(z0.z, w0.z, a2);
    a3 = fmaf(z0.w, w0.w, a3);
    a4 = fmaf(z1.x, w1.x, a4);
    a5 = fmaf(z1.y, w1.y, a5);
    a6 = fmaf(z1.z, w1.z, a6);
    a7 = fmaf(z1.w, w1.w, a7);
  }
  partial[bid * 256 + tid] = ((a0 + a1) + (a2 + a3)) + ((a4 + a5) + (a6 + a7));
}

// ======== red: partial[2250][256] -> red[90][256] (25 rows per block) ========
__global__ __launch_bounds__(256) void k_red(const float* __restrict__ partial,
                                             float* __restrict__ red) {
  const int bl = blockIdx.x, tid = threadIdx.x;
  const float* __restrict__ p = partial + bl * 25 * 256 + tid;
  float s0 = 0.f, s1 = 0.f, s2 = 0.f, s3 = 0.f, s4 = 0.f;
#pragma unroll
  for (int i = 0; i < 25; i += 5) {
    s0 += p[i * 256];
    s1 += p[(i + 1) * 256];
    s2 += p[(i + 2) * 256];
    s3 += p[(i + 3) * 256];
    s4 += p[(i + 4) * 256];
  }
  red[bl * 256 + tid] = ((s0 + s1) + (s2 + s3)) + s4;
}

// ======== head: reduce red[90][256] -> fc1 relu -> fc2 tanh -> R, Tv ========
__global__ __launch_bounds__(256) void k_head(const float* __restrict__ red,
                                              const float* __restrict__ fc1_b,
                                              const float* __restrict__ fc2_w,
                                              const float* __restrict__ fc2_b,
                                              float* __restrict__ RT) {
  __shared__ float sH[256];
  __shared__ float sTh[8][24];
  const int tid = threadIdx.x;
  float s0 = 0.f, s1 = 0.f, s2 = 0.f, s3 = 0.f, s4 = 0.f;
#pragma unroll
  for (int c = 0; c < 90; c += 5) {
    s0 += red[c * 256 + tid];
    s1 += red[(c + 1) * 256 + tid];
    s2 += red[(c + 2) * 256 + tid];
    s3 += red[(c + 3) * 256 + tid];
    s4 += red[(c + 4) * 256 + tid];
  }
  const int o = tid & 31;
  sH[tid] = fmaxf(((s0 + s1) + (s2 + s3)) + s4 + fc1_b[o], 0.f);
  __syncthreads();
  if (tid < 192) {
    int b = tid / 24, o2 = tid % 24;
    float a = fc2_b[o2];
#pragma unroll
    for (int i = 0; i < 32; ++i) a = fmaf(sH[b * 32 + i], fc2_w[o2 * 32 + i], a);
    sTh[b][o2] = tanhf(a);
  }
  __syncthreads();
  if (tid < 32) {
    const int b = tid >> 2, t = tid & 3;
    const float PI = 3.14159265358979323846f;
    float a0 = PI * sTh[b][t * 6 + 0];
    float a1 = PI * sTh[b][t * 6 + 1];
    float a2 = PI * sTh[b][t * 6 + 2];
    float t0 = sTh[b][t * 6 + 3], t1 = sTh[b][t * 6 + 4], t2 = sTh[b][t * 6 + 5];
    float c0 = cosf(a0), s0v = sinf(a0);
    float c1 = cosf(a1), s1v = sinf(a1);
    float c2 = cosf(a2), s2v = sinf(a2);
    float R[3][3];
    R[0][0] = c0 * c1;
    R[0][1] = c0 * s1v * s2v - s0v * c2;
    R[0][2] = c0 * s1v * c2 + s0v * s2v;
    R[1][0] = s0v * c1;
    R[1][1] = s0v * s1v * s2v + c0 * c2;
    R[1][2] = s0v * s1v * c2 - c0 * s2v;
    R[2][0] = -s1v;
    R[2][1] = c1 * s2v;
    R[2][2] = c1 * c2;
    const float SZv[3] = {256.f, 256.f, 16.f};
    const float cen[3] = {128.f, 128.f, 8.f};
    const float tr[3] = {t0, t1, t2};
    float* rt = RT + (b * 4 + t) * 12;
#pragma unroll
    for (int kq = 0; kq < 3; ++kq)
#pragma unroll
      for (int s = 0; s < 3; ++s) rt[kq * 3 + s] = R[kq][s];
#pragma unroll
    for (int s = 0; s < 3; ++s)
      rt[9 + s] = tr[s] * SZv[s] + cen[s] - (128.f * R[0][s] + 128.f * R[1][s] + 8.f * R[2][s]);
  }
}

// ====== flow + grid_out + trilinear grid-sample -> X_t ======
// R13 structure: per-VMEM-instruction cost is the proven limiter; this is its
// instruction-count floor (16 gather + 7 store VMEM instr/thread).
__global__ __launch_bounds__(256) void k_flow(const float* __restrict__ x,
                                              const float* __restrict__ RT,
                                              float* __restrict__ out) {
  const int raw = blockIdx.x;
  const int bid = (raw & 7) * 4096 + (raw >> 3);   // XCD-contiguous chunk
  const int tid = threadIdx.x;
  const int b = bid >> 12;
  const int l = ((bid & 4095) << 8) | tid;
  const int i = l >> 12, j = (l >> 4) & 255, k = l & 15;
  const float fi = (float)i, fj = (float)j, fk = (float)k;
  const float* __restrict__ rt = RT + b * 48;

  const float txs[4] = {64.f, 64.f, 192.f, 192.f};
  const float tys[4] = {64.f, 192.f, 64.f, 192.f};
  float e[4], es = 0.f;
#pragma unroll
  for (int t = 0; t < 4; ++t) {
    float dx = fi - txs[t], dy = fj - tys[t], dz = fk - 8.f;
    float d = __builtin_amdgcn_sqrtf(fmaf(dx, dx, fmaf(dy, dy, dz * dz)));
    e[t] = __expf(-0.1f * d);
    es += e[t];
  }
  float inv = __builtin_amdgcn_rcpf(es);
  float f0 = 0.f, f1 = 0.f, f2 = 0.f;
#pragma unroll
  for (int t = 0; t < 4; ++t) {
    float wt = e[t] * inv;
    const float* r = rt + t * 12;
    f0 += wt * (fi * r[0] + fj * r[3] + fk * r[6] + r[9]);
    f1 += wt * (fi * r[1] + fj * r[4] + fk * r[7] + r[10]);
    f2 += wt * (fi * r[2] + fj * r[5] + fk * r[8] + r[11]);
  }
  float nf0 = f0 * (1.f / 128.f) - 1.f;
  float nf1 = f1 * (1.f / 128.f) - 1.f;
  float nf2 = f2 * 0.125f - 1.f;

  int gbase = OUT_GRID + ((b << 20) + l) * 3;
  __builtin_nontemporal_store(nf2, &out[gbase]);
  __builtin_nontemporal_store(nf1, &out[gbase + 1]);
  __builtin_nontemporal_store(nf0, &out[gbase + 2]);

  float ix = ((nf2 + 1.f) * 16.f - 1.f) * 0.5f;
  float iy = ((nf1 + 1.f) * 256.f - 1.f) * 0.5f;
  float iz = ((nf0 + 1.f) * 256.f - 1.f) * 0.5f;
  float xf = floorf(ix), yf = floorf(iy), zf = floorf(iz);
  float fx = ix - xf, fy = iy - yf, fz = iz - zf;
  int x0 = (int)xf, y0 = (int)yf, z0 = (int)zf;
  int x1 = x0 + 1, y1 = y0 + 1, z1 = z0 + 1;
  bool vx0 = ((unsigned)x0 < 16u), vx1 = ((unsigned)x1 < 16u);
  bool vy0 = ((unsigned)y0 < 256u), vy1 = ((unsigned)y1 < 256u);
  bool vz0 = ((unsigned)z0 < 256u), vz1 = ((unsigned)z1 < 256u);
  int cx0 = min(max(x0, 0), 15), cx1 = min(max(x1, 0), 15);
  int cy0 = min(max(y0, 0), 255), cy1 = min(max(y1, 0), 255);
  int cz0 = min(max(z0, 0), 255), cz1 = min(max(z1, 0), 255);
  float wx0 = 1.f - fx, wx1 = fx, wy0 = 1.f - fy, wy1 = fy, wz0 = 1.f - fz, wz1 = fz;

  const float wxa = vx0 ? wx0 : 0.f;
  const float wxb = vx1 ? wx1 : 0.f;
  const int base_x = min(cx0, 14);
  const int i0 = cx0 - base_x;
  const int i1 = cx1 - base_x;
  const float ca = (i0 ? 0.f : wxa) + (i1 ? 0.f : wxb);
  const float cb = (i0 ? wxa : 0.f) + (i1 ? wxb : 0.f);

  float W4[4];
  W4[0] = wz0 * wy0 * ((vz0 && vy0) ? 1.f : 0.f);
  W4[1] = wz0 * wy1 * ((vz0 && vy1) ? 1.f : 0.f);
  W4[2] = wz1 * wy0 * ((vz1 && vy0) ? 1.f : 0.f);
  W4[3] = wz1 * wy1 * ((vz1 && vy1) ? 1.f : 0.f);

  int ro[4];
  ro[0] = (cz0 << 12) + (cy0 << 4) + base_x;
  ro[1] = (cz0 << 12) + (cy1 << 4) + base_x;
  ro[2] = (cz1 << 12) + (cy0 << 4) + base_x;
  ro[3] = (cz1 << 12) + (cy1 << 4) + base_x;

  const float* __restrict__ xb0 = x + ((size_t)(b * 4) << 20);

  {
    float2 fa[4], fb[4];
#pragma unroll
    for (int q = 0; q < 4; ++q) __builtin_memcpy(&fa[q], xb0 + ro[q], 8);
#pragma unroll
    for (int q = 0; q < 4; ++q) __builtin_memcpy(&fb[q], xb0 + (1 << 20) + ro[q], 8);
    float s0 = 0.f, s1 = 0.f;
#pragma unroll
    for (int q = 0; q < 4; ++q) {
      s0 = fmaf(W4[q], fmaf(cb, fa[q].y, ca * fa[q].x), s0);
      s1 = fmaf(W4[q], fmaf(cb, fb[q].y, ca * fb[q].x), s1);
    }
    __builtin_nontemporal_store(s0, &out[OUT_XT + ((b * 4 + 0) << 20) + l]);
    __builtin_nontemporal_store(s1, &out[OUT_XT + ((b * 4 + 1) << 20) + l]);
  }
  {
    float2 fa[4], fb[4];
#pragma unroll
    for (int q = 0; q < 4; ++q) __builtin_memcpy(&fa[q], xb0 + (2 << 20) + ro[q], 8);
#pragma unroll
    for (int q = 0; q < 4; ++q) __builtin_memcpy(&fb[q], xb0 + (3 << 20) + ro[q], 8);
    float s0 = 0.f, s1 = 0.f;
#pragma unroll
    for (int q = 0; q < 4; ++q) {
      s0 = fmaf(W4[q], fmaf(cb, fa[q].y, ca * fa[q].x), s0);
      s1 = fmaf(W4[q], fmaf(cb, fb[q].y, ca * fb[q].x), s1);
    }
    __builtin_nontemporal_store(s0, &out[OUT_XT + ((b * 4 + 2) << 20) + l]);
    __builtin_nontemporal_store(s1, &out[OUT_XT + ((b * 4 + 3) << 20) + l]);
  }
}

// ====== moved + reg ======
__global__ __launch_bounds__(256) void k_tail(const float* __restrict__ P,
                                              const float* __restrict__ centers,
                                              const int* __restrict__ times,
                                              float* __restrict__ out) {
  const int b = blockIdx.x, tid = threadIdx.x;
  __shared__ float sred[256];
  float nrm = 0.f;
  if (tid < 200) {
    int tb = times[b];
    float p0 = P[tid * 96 + tb];
    float p1 = P[tid * 96 + 32 + tb];
    float p2 = P[tid * 96 + 64 + tb];
    int i0 = (int)rintf(p0), i1 = (int)rintf(p1), i2 = (int)rintf(p2);
    int lp = (i0 << 12) + (i1 << 4) + i2;
    int gb = OUT_GRID + ((b << 20) + lp) * 3;
    float a0 = out[gb + 2];
    float a1 = out[gb + 1];
    float a2 = out[gb + 0];
    float m0 = 2.f * p0 - (0.5f + 0.5f * a0) * 255.f;
    float m1 = 2.f * p1 - (0.5f + 0.5f * a1) * 255.f;
    float m2 = 2.f * p2 - (0.5f + 0.5f * a2) * 15.f;
    int mo = OUT_MOVED + (b * 200 + tid) * 3;
    out[mo] = m0;
    out[mo + 1] = m1;
    out[mo + 2] = m2;
    float d0 = m0 - centers[tid * 3];
    float d1 = m1 - centers[tid * 3 + 1];
    float d2 = m2 - centers[tid * 3 + 2];
    nrm = sqrtf(d0 * d0 + d1 * d1 + d2 * d2);
  }
  sred[tid] = nrm;
  __syncthreads();
  for (int s = 128; s > 0; s >>= 1) {
    if (tid < s) sred[tid] += sred[tid + s];
    __syncthreads();
  }
  if (tid == 0) out[OUT_REG + b] = sred[0] * 0.005f;
}

extern "C" void kernel_launch(void* const* d_in, const int* in_sizes, int n_in,
                              void* d_out, int out_size, void* d_ws, size_t ws_size,
                              hipStream_t stream) {
  const float* x = (const float*)d_in[0];
  const int* times = (const int*)d_in[1];
  const float* w1 = (const float*)d_in[2];
  const float* b1 = (const float*)d_in[3];
  const float* w2 = (const float*)d_in[4];
  const float* b2 = (const float*)d_in[5];
  const float* fw1 = (const float*)d_in[6];
  const float* fb1 = (const float*)d_in[7];
  const float* fw2 = (const float*)d_in[8];
  const float* fb2 = (const float*)d_in[9];
  const float* P = (const float*)d_in[10];
  const float* centers = (const float*)d_in[11];
  float* out = (float*)d_out;

  float* wt1 = (float*)d_ws;          // 1568 floats
  float* wt2 = wt1 + 1568;            // 2000 floats

  float* buf1 = out + WS_BUF1;
  float* buf2 = out + WS_BUF2;
  float* partial = out + WS_PART;
  float* red = out + WS_RED;
  float* RT = out + WS_RT;

  k_prep<<<1, 256, 0, stream>>>(w1, w2, wt1, wt2);
  k_conv1<<<dim3(16, 32, 8), 256, 0, stream>>>(x, wt1, b1, buf1);
  k_conv2<<<dim3(8, 15, 8), 256, 0, stream>>>(buf1, wt2, b2, buf2);
  k_fc1<<<2250, 256, 0, stream>>>(buf2, fw1, partial);
  k_red<<<90, 256, 0, stream>>>(partial, red);
  k_head<<<1, 256, 0, stream>>>(red, fb1, fw2, fb2, RT);
  k_flow<<<32768, 256, 0, stream>>>(x, RT, out);
  k_tail<<<8, 256, 0, stream>>>(P, centers, times, out);
}

// Round 19
// 429.135 us; speedup vs baseline: 1.4416x; 1.0595x over previous
//
#include <hip/hip_runtime.h>
#include <math.h>

// ---- problem constants ----
#define OUT_XT     0
#define OUT_GRID   33554432
#define OUT_REG    58720256
#define OUT_MOVED  58720264
#define FC1_K      576000

// scratch inside d_out (regions consumed before being overwritten):
#define WS_BUF1    0          // (8,8,125,125,16) -- inside X_t region
#define WS_BUF2    16000000   // (8,10,60,60,16)
#define WS_PART    20608000   // 2250 x 256 = 576000
#define WS_RED     21184000   // 90 x 256
#define WS_RT      58720256   // 8x4x12 -- reg+moved region, overwritten by k_tail

typedef __fp16 half2v __attribute__((ext_vector_type(2)));

__device__ __forceinline__ unsigned int packh2(float a, float b) {
  half2v h = __builtin_amdgcn_cvt_pkrtz(a, b);
  return __builtin_bit_cast(unsigned int, h);
}

// dot2: c += a.lo*b.lo + a.hi*b.hi  (fp16 inputs, fp32 accumulate)
__device__ __forceinline__ float dot2f(unsigned int a, unsigned int b, float c) {
#if __has_builtin(__builtin_amdgcn_fdot2)
  return __builtin_amdgcn_fdot2(__builtin_bit_cast(half2v, a),
                                __builtin_bit_cast(half2v, b), c, false);
#else
  half2v ha = __builtin_bit_cast(half2v, a);
  half2v hb = __builtin_bit_cast(half2v, b);
  return fmaf((float)ha.y, (float)hb.y, fmaf((float)ha.x, (float)hb.x, c));
#endif
}

// ======== prep: pack weights as half2 ic-pairs, [icp][dd][oc] layout ========
__global__ __launch_bounds__(256) void k_prep(const float* __restrict__ w1,
                                              const float* __restrict__ w2,
                                              unsigned int* __restrict__ wt1p,
                                              unsigned int* __restrict__ wt2p) {
  const int tid = threadIdx.x;
  for (int t = tid; t < 784; t += 256) {        // 2 icp x 49 dd x 8 oc
    int oc = t & 7, idx = t >> 3;
    int icp = idx / 49, dd = idx % 49;
    float lo = w1[(oc * 4 + 2 * icp) * 49 + dd];
    float hi = w1[(oc * 4 + 2 * icp + 1) * 49 + dd];
    wt1p[t] = packh2(lo, hi);
  }
  for (int t = tid; t < 1000; t += 256) {       // 4 icp x 25 dd x 10 oc
    int oc = t % 10, idx = t / 10;
    int icp = idx / 25, dd = idx % 25;
    float lo = w2[(oc * 8 + 2 * icp) * 25 + dd];
    float hi = w2[(oc * 8 + 2 * icp + 1) * 25 + dd];
    wt2p[t] = packh2(lo, hi);
  }
}

// ================= conv1 (7x7x1, 4->8) + pool(2,2,1) + relu =================
// R19: fp16 dot2 ic-pair packing (2 MAC/instr, fp32 accumulate) -> FMA instr
// count halves. LDS holds one ic-pair as half2 (uint), same geometry/pad as the
// proven fp32 tile (PS=322 == 2 mod 32: conflict-free b64 reads).
#define C1_RS 22
#define C1_PS 322
__global__ __launch_bounds__(256) void k_conv1(const float* __restrict__ x,
                                               const unsigned int* __restrict__ wt1p,
                                               const float* __restrict__ b1,
                                               float* __restrict__ buf1) {
  __shared__ unsigned int sIn[16 * C1_PS];
  const int tid = threadIdx.x;
  const int tx = blockIdx.x, ty = blockIdx.y, b = blockIdx.z;

  const int k = tid & 15;
  const int pix = tid >> 4;
  const int pyl = pix >> 2, pxl = pix & 3;
  const int row0 = ty * 8, col0 = tx * 16;

  int sq[5], srow[5], scol[5], sbase[5];
  bool sval[5];
#pragma unroll
  for (int it = 0; it < 5; ++it) {
    int t = tid + it * 256;
    int q = t & 3, pos = t >> 2;
    int coli = pos % 22, rowi = pos / 22;
    sq[it] = q;
    srow[it] = row0 + rowi;
    scol[it] = col0 + coli;
    sbase[it] = rowi * C1_RS + coli;
    sval[it] = (t < 1232) && (srow[it] < 256) && (scol[it] < 256);
  }

  const float4* __restrict__ x4 = reinterpret_cast<const float4*>(x);
  float4 sta[5], stb[5];

#define C1_LOAD(ICP) do {                                                    \
  _Pragma("unroll")                                                          \
  for (int it = 0; it < 5; ++it) {                                           \
    float4 va = make_float4(0.f, 0.f, 0.f, 0.f);                             \
    float4 vb = va;                                                          \
    if (sval[it]) {                                                          \
      va = x4[(((b * 4 + 2 * (ICP)) * 256 + srow[it]) * 256 + scol[it]) * 4 + sq[it]]; \
      vb = x4[(((b * 4 + 2 * (ICP) + 1) * 256 + srow[it]) * 256 + scol[it]) * 4 + sq[it]]; \
    }                                                                        \
    sta[it] = va;                                                            \
    stb[it] = vb;                                                            \
  } } while (0)

#define C1_WRITE() do {                                                      \
  _Pragma("unroll")                                                          \
  for (int it = 0; it < 5; ++it) {                                           \
    if (it < 4 || tid < 208) {                                               \
      unsigned int* sp = &sIn[(4 * sq[it]) * C1_PS + sbase[it]];             \
      sp[0 * C1_PS] = packh2(sta[it].x, stb[it].x);                          \
      sp[1 * C1_PS] = packh2(sta[it].y, stb[it].y);                          \
      sp[2 * C1_PS] = packh2(sta[it].z, stb[it].z);                          \
      sp[3 * C1_PS] = packh2(sta[it].w, stb[it].w);                          \
    }                                                                        \
  } } while (0)

  float acc[2][4][8];
#pragma unroll
  for (int a = 0; a < 2; ++a)
#pragma unroll
    for (int c = 0; c < 4; ++c)
#pragma unroll
      for (int oc = 0; oc < 8; ++oc) acc[a][c][oc] = 0.f;

  C1_LOAD(0);
  C1_WRITE();
  __syncthreads();

#pragma unroll 1
  for (int icp = 0; icp < 2; ++icp) {
    if (icp == 0) C1_LOAD(1);           // T14: HBM latency hides under compute
#pragma unroll 1
    for (int dy = 0; dy < 7; ++dy) {
      unsigned int v2[2][10];
#pragma unroll
      for (int a = 0; a < 2; ++a) {
        const int base = k * C1_PS + (2 * pyl + a + dy) * C1_RS + 4 * pxl;
#pragma unroll
        for (int j = 0; j < 5; ++j) {
          uint2 f = *reinterpret_cast<const uint2*>(&sIn[base + 2 * j]);
          v2[a][2 * j] = f.x;
          v2[a][2 * j + 1] = f.y;
        }
      }
      const unsigned int* __restrict__ wd = wt1p + (icp * 49 + dy * 7) * 8;  // uniform -> s_load
#pragma unroll
      for (int dx = 0; dx < 7; ++dx) {
#pragma unroll
        for (int a = 0; a < 2; ++a)
#pragma unroll
          for (int c = 0; c < 4; ++c) {
            const unsigned int val = v2[a][c + dx];
#pragma unroll
            for (int oc = 0; oc < 8; ++oc)
              acc[a][c][oc] = dot2f(val, wd[dx * 8 + oc], acc[a][c][oc]);
          }
      }
    }
    if (icp == 0) {
      __syncthreads();
      C1_WRITE();
      __syncthreads();
    }
  }
#undef C1_LOAD
#undef C1_WRITE

  const int py = ty * 4 + pyl;
  if (py < 125) {
#pragma unroll
    for (int cc = 0; cc < 2; ++cc) {
      const int px = tx * 8 + 2 * pxl + cc;
      if (px < 125) {
#pragma unroll
        for (int oc = 0; oc < 8; ++oc) {
          float m = fmaxf(fmaxf(acc[0][2 * cc][oc], acc[0][2 * cc + 1][oc]),
                          fmaxf(acc[1][2 * cc][oc], acc[1][2 * cc + 1][oc])) + b1[oc];
          buf1[(((b * 8 + oc) * 125 + py) * 125 + px) * 16 + k] = fmaxf(m, 0.f);
        }
      }
    }
  }
}

// ================= conv2 (5x5x1, 8->10) + pool + relu =================
// dot2 ic-pair packing: 4 pairs, 2 MAC/instr fp32-accum.
#define C2_RS 20
#define C2_PS 258
__global__ __launch_bounds__(256) void k_conv2(const float* __restrict__ in,
                                               const unsigned int* __restrict__ wt2p,
                                               const float* __restrict__ b2,
                                               float* __restrict__ buf2) {
  __shared__ unsigned int sIn[16 * C2_PS];
  const int tid = threadIdx.x;
  const int tx = blockIdx.x, ty = blockIdx.y, b = blockIdx.z;

  const int k = tid & 15;
  const int pix = tid >> 4;
  const int pyl = pix >> 2, pxl = pix & 3;
  const int row0 = ty * 8, col0 = tx * 16;

  int sq[4], srow[4], scol[4], sbase[4];
  bool sval[4];
#pragma unroll
  for (int it = 0; it < 4; ++it) {
    int t = tid + it * 256;
    int q = t & 3, pos = t >> 2;
    int coli = pos % 20, rowi = pos / 20;
    sq[it] = q;
    srow[it] = row0 + rowi;
    scol[it] = col0 + coli;
    sbase[it] = rowi * C2_RS + coli;
    sval[it] = (t < 960) && (scol[it] < 125);
  }

  const float4* __restrict__ in4 = reinterpret_cast<const float4*>(in);
  float4 sta[4], stb[4];

#define C2_LOAD(ICP) do {                                                    \
  _Pragma("unroll")                                                          \
  for (int it = 0; it < 4; ++it) {                                           \
    float4 va = make_float4(0.f, 0.f, 0.f, 0.f);                             \
    float4 vb = va;                                                          \
    if (sval[it]) {                                                          \
      va = in4[(((b * 8 + 2 * (ICP)) * 125 + srow[it]) * 125 + scol[it]) * 4 + sq[it]]; \
      vb = in4[(((b * 8 + 2 * (ICP) + 1) * 125 + srow[it]) * 125 + scol[it]) * 4 + sq[it]]; \
    }                                                                        \
    sta[it] = va;                                                            \
    stb[it] = vb;                                                            \
  } } while (0)

#define C2_WRITE() do {                                                      \
  _Pragma("unroll")                                                          \
  for (int it = 0; it < 4; ++it) {                                           \
    if (it < 3 || tid < 192) {                                               \
      unsigned int* sp = &sIn[(4 * sq[it]) * C2_PS + sbase[it]];             \
      sp[0 * C2_PS] = packh2(sta[it].x, stb[it].x);                          \
      sp[1 * C2_PS] = packh2(sta[it].y, stb[it].y);                          \
      sp[2 * C2_PS] = packh2(sta[it].z, stb[it].z);                          \
      sp[3 * C2_PS] = packh2(sta[it].w, stb[it].w);                          \
    }                                                                        \
  } } while (0)

  float acc[2][4][10];
#pragma unroll
  for (int a = 0; a < 2; ++a)
#pragma unroll
    for (int c = 0; c < 4; ++c)
#pragma unroll
      for (int oc = 0; oc < 10; ++oc) acc[a][c][oc] = 0.f;

  C2_LOAD(0);
  C2_WRITE();
  __syncthreads();

#pragma unroll 1
  for (int icp = 0; icp < 4; ++icp) {
    if (icp < 3) C2_LOAD(icp + 1);
#pragma unroll 1
    for (int dy = 0; dy < 5; ++dy) {
      unsigned int v2[2][8];
#pragma unroll
      for (int a = 0; a < 2; ++a) {
        const int base = k * C2_PS + (2 * pyl + a + dy) * C2_RS + 4 * pxl;
#pragma unroll
        for (int j = 0; j < 4; ++j) {
          uint2 f = *reinterpret_cast<const uint2*>(&sIn[base + 2 * j]);
          v2[a][2 * j] = f.x;
          v2[a][2 * j + 1] = f.y;
        }
      }
      const unsigned int* __restrict__ wd = wt2p + (icp * 25 + dy * 5) * 10;  // uniform
#pragma unroll
      for (int dx = 0; dx < 5; ++dx) {
#pragma unroll
        for (int a = 0; a < 2; ++a)
#pragma unroll
          for (int c = 0; c < 4; ++c) {
            const unsigned int val = v2[a][c + dx];
#pragma unroll
            for (int oc = 0; oc < 10; ++oc)
              acc[a][c][oc] = dot2f(val, wd[dx * 10 + oc], acc[a][c][oc]);
          }
      }
    }
    if (icp < 3) {
      __syncthreads();
      C2_WRITE();
      __syncthreads();
    }
  }
#undef C2_LOAD
#undef C2_WRITE

  const int py = ty * 4 + pyl;
#pragma unroll
  for (int cc = 0; cc < 2; ++cc) {
    const int px = tx * 8 + 2 * pxl + cc;
    if (px < 60) {
#pragma unroll
      for (int oc = 0; oc < 10; ++oc) {
        float m = fmaxf(fmaxf(acc[0][2 * cc][oc], acc[0][2 * cc + 1][oc]),
                        fmaxf(acc[1][2 * cc][oc], acc[1][2 * cc + 1][oc])) + b2[oc];
        buf2[(((b * 10 + oc) * 60 + py) * 60 + px) * 16 + k] = fmaxf(m, 0.f);
      }
    }
  }
}

// ================= fc1 split-K: coalesced via LDS bounce (R17, proven) =======
__global__ __launch_bounds__(256) void k_fc1(const float* __restrict__ z,
                                             const float* __restrict__ w,
                                             float* __restrict__ partial) {
  __shared__ float sW[32 * 260];
  __shared__ float sZ[8 * 256];
  const int bid = blockIdx.x, tid = threadIdx.x;
  const int k0 = bid * 256;

  for (int t = tid; t < 2048; t += 256) {
    int o = t >> 6, kq = t & 63;
    float4 v = *reinterpret_cast<const float4*>(w + o * FC1_K + k0 + 4 * kq);
    *reinterpret_cast<float4*>(&sW[o * 260 + 4 * kq]) = v;
  }
  for (int t = tid; t < 512; t += 256) {
    int b = t >> 6, kq = t & 63;
    *reinterpret_cast<float4*>(&sZ[b * 256 + 4 * kq]) =
        *reinterpret_cast<const float4*>(z + b * FC1_K + k0 + 4 * kq);
  }
  __syncthreads();

  const int b = tid >> 5, o = tid & 31;
  const float* __restrict__ zp = &sZ[b * 256];
  const float* __restrict__ wp = &sW[o * 260];
  float a0 = 0.f, a1 = 0.f, a2 = 0.f, a3 = 0.f;
  float a4 = 0.f, a5 = 0.f, a6 = 0.f, a7 = 0.f;
#pragma unroll
  for (int kk = 0; kk < 256; kk += 8) {
    float4 z0 = *reinterpret_cast<const float4*>(zp + kk);
    float4 w0 = *reinterpret_cast<const float4*>(wp + kk);
    float4 z1 = *reinterpret_cast<const float4*>(zp + kk + 4);
    float4 w1 = *reinterpret_cast<const float4*>(wp + kk + 4);
    a0 = fmaf(z0.x, w0.x, a0);
    a1 = fmaf(z0.y, w0.y, a1);
    a2 = fmaf(z0.z, w0.z, a2);
    a3 = fmaf(z0.w, w0.w, a3);
    a4 = fmaf(z1.x, w1.x, a4);
    a5 = fmaf(z1.y, w1.y, a5);
    a6 = fmaf(z1.z, w1.z, a6);
    a7 = fmaf(z1.w, w1.w, a7);
  }
  partial[bid * 256 + tid] = ((a0 + a1) + (a2 + a3)) + ((a4 + a5) + (a6 + a7));
}

// ======== red: partial[2250][256] -> red[90][256] ========
__global__ __launch_bounds__(256) void k_red(const float* __restrict__ partial,
                                             float* __restrict__ red) {
  const int bl = blockIdx.x, tid = threadIdx.x;
  const float* __restrict__ p = partial + bl * 25 * 256 + tid;
  float s0 = 0.f, s1 = 0.f, s2 = 0.f, s3 = 0.f, s4 = 0.f;
#pragma unroll
  for (int i = 0; i < 25; i += 5) {
    s0 += p[i * 256];
    s1 += p[(i + 1) * 256];
    s2 += p[(i + 2) * 256];
    s3 += p[(i + 3) * 256];
    s4 += p[(i + 4) * 256];
  }
  red[bl * 256 + tid] = ((s0 + s1) + (s2 + s3)) + s4;
}

// ======== head: reduce red[90][256] -> fc1 relu -> fc2 tanh -> R, Tv ========
__global__ __launch_bounds__(256) void k_head(const float* __restrict__ red,
                                              const float* __restrict__ fc1_b,
                                              const float* __restrict__ fc2_w,
                                              const float* __restrict__ fc2_b,
                                              float* __restrict__ RT) {
  __shared__ float sH[256];
  __shared__ float sTh[8][24];
  const int tid = threadIdx.x;
  float s0 = 0.f, s1 = 0.f, s2 = 0.f, s3 = 0.f, s4 = 0.f;
#pragma unroll
  for (int c = 0; c < 90; c += 5) {
    s0 += red[c * 256 + tid];
    s1 += red[(c + 1) * 256 + tid];
    s2 += red[(c + 2) * 256 + tid];
    s3 += red[(c + 3) * 256 + tid];
    s4 += red[(c + 4) * 256 + tid];
  }
  const int o = tid & 31;
  sH[tid] = fmaxf(((s0 + s1) + (s2 + s3)) + s4 + fc1_b[o], 0.f);
  __syncthreads();
  if (tid < 192) {
    int b = tid / 24, o2 = tid % 24;
    float a = fc2_b[o2];
#pragma unroll
    for (int i = 0; i < 32; ++i) a = fmaf(sH[b * 32 + i], fc2_w[o2 * 32 + i], a);
    sTh[b][o2] = tanhf(a);
  }
  __syncthreads();
  if (tid < 32) {
    const int b = tid >> 2, t = tid & 3;
    const float PI = 3.14159265358979323846f;
    float a0 = PI * sTh[b][t * 6 + 0];
    float a1 = PI * sTh[b][t * 6 + 1];
    float a2 = PI * sTh[b][t * 6 + 2];
    float t0 = sTh[b][t * 6 + 3], t1 = sTh[b][t * 6 + 4], t2 = sTh[b][t * 6 + 5];
    float c0 = cosf(a0), s0v = sinf(a0);
    float c1 = cosf(a1), s1v = sinf(a1);
    float c2 = cosf(a2), s2v = sinf(a2);
    float R[3][3];
    R[0][0] = c0 * c1;
    R[0][1] = c0 * s1v * s2v - s0v * c2;
    R[0][2] = c0 * s1v * c2 + s0v * s2v;
    R[1][0] = s0v * c1;
    R[1][1] = s0v * s1v * s2v + c0 * c2;
    R[1][2] = s0v * s1v * c2 - c0 * s2v;
    R[2][0] = -s1v;
    R[2][1] = c1 * s2v;
    R[2][2] = c1 * c2;
    const float SZv[3] = {256.f, 256.f, 16.f};
    const float cen[3] = {128.f, 128.f, 8.f};
    const float tr[3] = {t0, t1, t2};
    float* rt = RT + (b * 4 + t) * 12;
#pragma unroll
    for (int kq = 0; kq < 3; ++kq)
#pragma unroll
      for (int s = 0; s < 3; ++s) rt[kq * 3 + s] = R[kq][s];
#pragma unroll
    for (int s = 0; s < 3; ++s)
      rt[9 + s] = tr[s] * SZv[s] + cen[s] - (128.f * R[0][s] + 128.f * R[1][s] + 8.f * R[2][s]);
  }
}

// ====== flow + grid_out + trilinear grid-sample -> X_t (R13, proven floor) ======
__global__ __launch_bounds__(256) void k_flow(const float* __restrict__ x,
                                              const float* __restrict__ RT,
                                              float* __restrict__ out) {
  const int raw = blockIdx.x;
  const int bid = (raw & 7) * 4096 + (raw >> 3);   // XCD-contiguous chunk
  const int tid = threadIdx.x;
  const int b = bid >> 12;
  const int l = ((bid & 4095) << 8) | tid;
  const int i = l >> 12, j = (l >> 4) & 255, k = l & 15;
  const float fi = (float)i, fj = (float)j, fk = (float)k;
  const float* __restrict__ rt = RT + b * 48;

  const float txs[4] = {64.f, 64.f, 192.f, 192.f};
  const float tys[4] = {64.f, 192.f, 64.f, 192.f};
  float e[4], es = 0.f;
#pragma unroll
  for (int t = 0; t < 4; ++t) {
    float dx = fi - txs[t], dy = fj - tys[t], dz = fk - 8.f;
    float d = __builtin_amdgcn_sqrtf(fmaf(dx, dx, fmaf(dy, dy, dz * dz)));
    e[t] = __expf(-0.1f * d);
    es += e[t];
  }
  float inv = __builtin_amdgcn_rcpf(es);
  float f0 = 0.f, f1 = 0.f, f2 = 0.f;
#pragma unroll
  for (int t = 0; t < 4; ++t) {
    float wt = e[t] * inv;
    const float* r = rt + t * 12;
    f0 += wt * (fi * r[0] + fj * r[3] + fk * r[6] + r[9]);
    f1 += wt * (fi * r[1] + fj * r[4] + fk * r[7] + r[10]);
    f2 += wt * (fi * r[2] + fj * r[5] + fk * r[8] + r[11]);
  }
  float nf0 = f0 * (1.f / 128.f) - 1.f;
  float nf1 = f1 * (1.f / 128.f) - 1.f;
  float nf2 = f2 * 0.125f - 1.f;

  int gbase = OUT_GRID + ((b << 20) + l) * 3;
  __builtin_nontemporal_store(nf2, &out[gbase]);
  __builtin_nontemporal_store(nf1, &out[gbase + 1]);
  __builtin_nontemporal_store(nf0, &out[gbase + 2]);

  float ix = ((nf2 + 1.f) * 16.f - 1.f) * 0.5f;
  float iy = ((nf1 + 1.f) * 256.f - 1.f) * 0.5f;
  float iz = ((nf0 + 1.f) * 256.f - 1.f) * 0.5f;
  float xf = floorf(ix), yf = floorf(iy), zf = floorf(iz);
  float fx = ix - xf, fy = iy - yf, fz = iz - zf;
  int x0 = (int)xf, y0 = (int)yf, z0 = (int)zf;
  int x1 = x0 + 1, y1 = y0 + 1, z1 = z0 + 1;
  bool vx0 = ((unsigned)x0 < 16u), vx1 = ((unsigned)x1 < 16u);
  bool vy0 = ((unsigned)y0 < 256u), vy1 = ((unsigned)y1 < 256u);
  bool vz0 = ((unsigned)z0 < 256u), vz1 = ((unsigned)z1 < 256u);
  int cx0 = min(max(x0, 0), 15), cx1 = min(max(x1, 0), 15);
  int cy0 = min(max(y0, 0), 255), cy1 = min(max(y1, 0), 255);
  int cz0 = min(max(z0, 0), 255), cz1 = min(max(z1, 0), 255);
  float wx0 = 1.f - fx, wx1 = fx, wy0 = 1.f - fy, wy1 = fy, wz0 = 1.f - fz, wz1 = fz;

  const float wxa = vx0 ? wx0 : 0.f;
  const float wxb = vx1 ? wx1 : 0.f;
  const int base_x = min(cx0, 14);
  const int i0 = cx0 - base_x;
  const int i1 = cx1 - base_x;
  const float ca = (i0 ? 0.f : wxa) + (i1 ? 0.f : wxb);
  const float cb = (i0 ? wxa : 0.f) + (i1 ? wxb : 0.f);

  float W4[4];
  W4[0] = wz0 * wy0 * ((vz0 && vy0) ? 1.f : 0.f);
  W4[1] = wz0 * wy1 * ((vz0 && vy1) ? 1.f : 0.f);
  W4[2] = wz1 * wy0 * ((vz1 && vy0) ? 1.f : 0.f);
  W4[3] = wz1 * wy1 * ((vz1 && vy1) ? 1.f : 0.f);

  int ro[4];
  ro[0] = (cz0 << 12) + (cy0 << 4) + base_x;
  ro[1] = (cz0 << 12) + (cy1 << 4) + base_x;
  ro[2] = (cz1 << 12) + (cy0 << 4) + base_x;
  ro[3] = (cz1 << 12) + (cy1 << 4) + base_x;

  const float* __restrict__ xb0 = x + ((size_t)(b * 4) << 20);

  {
    float2 fa[4], fb[4];
#pragma unroll
    for (int q = 0; q < 4; ++q) __builtin_memcpy(&fa[q], xb0 + ro[q], 8);
#pragma unroll
    for (int q = 0; q < 4; ++q) __builtin_memcpy(&fb[q], xb0 + (1 << 20) + ro[q], 8);
    float s0 = 0.f, s1 = 0.f;
#pragma unroll
    for (int q = 0; q < 4; ++q) {
      s0 = fmaf(W4[q], fmaf(cb, fa[q].y, ca * fa[q].x), s0);
      s1 = fmaf(W4[q], fmaf(cb, fb[q].y, ca * fb[q].x), s1);
    }
    __builtin_nontemporal_store(s0, &out[OUT_XT + ((b * 4 + 0) << 20) + l]);
    __builtin_nontemporal_store(s1, &out[OUT_XT + ((b * 4 + 1) << 20) + l]);
  }
  {
    float2 fa[4], fb[4];
#pragma unroll
    for (int q = 0; q < 4; ++q) __builtin_memcpy(&fa[q], xb0 + (2 << 20) + ro[q], 8);
#pragma unroll
    for (int q = 0; q < 4; ++q) __builtin_memcpy(&fb[q], xb0 + (3 << 20) + ro[q], 8);
    float s0 = 0.f, s1 = 0.f;
#pragma unroll
    for (int q = 0; q < 4; ++q) {
      s0 = fmaf(W4[q], fmaf(cb, fa[q].y, ca * fa[q].x), s0);
      s1 = fmaf(W4[q], fmaf(cb, fb[q].y, ca * fb[q].x), s1);
    }
    __builtin_nontemporal_store(s0, &out[OUT_XT + ((b * 4 + 2) << 20) + l]);
    __builtin_nontemporal_store(s1, &out[OUT_XT + ((b * 4 + 3) << 20) + l]);
  }
}

// ====== moved + reg ======
__global__ __launch_bounds__(256) void k_tail(const float* __restrict__ P,
                                              const float* __restrict__ centers,
                                              const int* __restrict__ times,
                                              float* __restrict__ out) {
  const int b = blockIdx.x, tid = threadIdx.x;
  __shared__ float sred[256];
  float nrm = 0.f;
  if (tid < 200) {
    int tb = times[b];
    float p0 = P[tid * 96 + tb];
    float p1 = P[tid * 96 + 32 + tb];
    float p2 = P[tid * 96 + 64 + tb];
    int i0 = (int)rintf(p0), i1 = (int)rintf(p1), i2 = (int)rintf(p2);
    int lp = (i0 << 12) + (i1 << 4) + i2;
    int gb = OUT_GRID + ((b << 20) + lp) * 3;
    float a0 = out[gb + 2];
    float a1 = out[gb + 1];
    float a2 = out[gb + 0];
    float m0 = 2.f * p0 - (0.5f + 0.5f * a0) * 255.f;
    float m1 = 2.f * p1 - (0.5f + 0.5f * a1) * 255.f;
    float m2 = 2.f * p2 - (0.5f + 0.5f * a2) * 15.f;
    int mo = OUT_MOVED + (b * 200 + tid) * 3;
    out[mo] = m0;
    out[mo + 1] = m1;
    out[mo + 2] = m2;
    float d0 = m0 - centers[tid * 3];
    float d1 = m1 - centers[tid * 3 + 1];
    float d2 = m2 - centers[tid * 3 + 2];
    nrm = sqrtf(d0 * d0 + d1 * d1 + d2 * d2);
  }
  sred[tid] = nrm;
  __syncthreads();
  for (int s = 128; s > 0; s >>= 1) {
    if (tid < s) sred[tid] += sred[tid + s];
    __syncthreads();
  }
  if (tid == 0) out[OUT_REG + b] = sred[0] * 0.005f;
}

extern "C" void kernel_launch(void* const* d_in, const int* in_sizes, int n_in,
                              void* d_out, int out_size, void* d_ws, size_t ws_size,
                              hipStream_t stream) {
  const float* x = (const float*)d_in[0];
  const int* times = (const int*)d_in[1];
  const float* w1 = (const float*)d_in[2];
  const float* b1 = (const float*)d_in[3];
  const float* w2 = (const float*)d_in[4];
  const float* b2 = (const float*)d_in[5];
  const float* fw1 = (const float*)d_in[6];
  const float* fb1 = (const float*)d_in[7];
  const float* fw2 = (const float*)d_in[8];
  const float* fb2 = (const float*)d_in[9];
  const float* P = (const float*)d_in[10];
  const float* centers = (const float*)d_in[11];
  float* out = (float*)d_out;

  unsigned int* wt1p = (unsigned int*)d_ws;   // 784 uints
  unsigned int* wt2p = wt1p + 784;            // 1000 uints

  float* buf1 = out + WS_BUF1;
  float* buf2 = out + WS_BUF2;
  float* partial = out + WS_PART;
  float* red = out + WS_RED;
  float* RT = out + WS_RT;

  k_prep<<<1, 256, 0, stream>>>(w1, w2, wt1p, wt2p);
  k_conv1<<<dim3(16, 32, 8), 256, 0, stream>>>(x, wt1p, b1, buf1);
  k_conv2<<<dim3(8, 15, 8), 256, 0, stream>>>(buf1, wt2p, b2, buf2);
  k_fc1<<<2250, 256, 0, stream>>>(buf2, fw1, partial);
  k_red<<<90, 256, 0, stream>>>(partial, red);
  k_head<<<1, 256, 0, stream>>>(red, fb1, fw2, fb2, RT);
  k_flow<<<32768, 256, 0, stream>>>(x, RT, out);
  k_tail<<<8, 256, 0, stream>>>(P, centers, times, out);
}